// Round 3
// baseline (5077.766 us; speedup 1.0000x reference)
//
#include <hip/hip_runtime.h>

#define N_NODES 50000
#define N_EDGES 800000
#define E2      850000        // N_EDGES + N_NODES (self loops)
#define NODE_IN 32
#define EDGE_IN 16
#define EMB     128
#define GAT_IN  160           // NODE_IN + EMB
#define NLAYER  2
#define NGRAPH  8

// ---------------------------------------------------------------------------
// zero fill (replaces hipMemsetAsync; graph-capture safe by construction)
// ---------------------------------------------------------------------------
__global__ void zero_kernel(float* __restrict__ p, int n) {
    int i = blockIdx.x * blockDim.x + threadIdx.x;
    int stride = gridDim.x * blockDim.x;
    for (; i < n; i += stride) p[i] = 0.f;
}

// ---------------------------------------------------------------------------
// mean of edge_attr over E edges -> meta[0..16) as sums (divided in prep)
// ---------------------------------------------------------------------------
__global__ __launch_bounds__(256) void mean_ea_kernel(const float* __restrict__ ea,
                                                      float* __restrict__ meta) {
    __shared__ float sm[EDGE_IN];
    int t = threadIdx.x;
    if (t < EDGE_IN) sm[t] = 0.f;
    __syncthreads();
    float s[EDGE_IN];
#pragma unroll
    for (int k = 0; k < EDGE_IN; k++) s[k] = 0.f;
    for (int e = blockIdx.x * blockDim.x + t; e < N_EDGES; e += gridDim.x * blockDim.x) {
        const float* row = ea + (size_t)e * EDGE_IN;
#pragma unroll
        for (int k = 0; k < EDGE_IN; k++) s[k] += row[k];
    }
#pragma unroll
    for (int k = 0; k < EDGE_IN; k++) atomicAdd(&sm[k], s[k]);
    __syncthreads();
    if (t < EDGE_IN) atomicAdd(&meta[t], sm[t]);
}

// ---------------------------------------------------------------------------
// prep: finish mean; M[l][k][h] = sum_c W_edge[l,k,h*32+c]*att_edge[l,h,c]
// -> meta[16..144); loop-edge a_e[l][h] = sum_k mean[k]*M[l][k][h] -> meta[144..152)
// ---------------------------------------------------------------------------
__global__ void prep_kernel(const float* __restrict__ W_edge,
                            const float* __restrict__ att_edge,
                            float* __restrict__ meta) {
    int t = threadIdx.x;  // 128 threads
    if (t < EDGE_IN) meta[t] = meta[t] * (1.0f / (float)N_EDGES);
    __syncthreads();
    {
        int l = t >> 6, k = (t >> 2) & 15, h = t & 3;
        const float* w = W_edge + ((size_t)l * EDGE_IN + k) * EMB + h * 32;
        const float* a = att_edge + (size_t)l * EMB + h * 32;
        float acc = 0.f;
#pragma unroll
        for (int c = 0; c < 32; c++) acc += w[c] * a[c];
        meta[16 + (l * 16 + k) * 4 + h] = acc;
    }
    __syncthreads();
    if (t < 8) {
        int l = t >> 2, h = t & 3;
        float acc = 0.f;
#pragma unroll
        for (int k = 0; k < EDGE_IN; k++) acc += meta[k] * meta[16 + (l * 16 + k) * 4 + h];
        meta[144 + t] = acc;
    }
}

// ---------------------------------------------------------------------------
// h = relu(x @ W_in + b_in); wave per node, lane = 2 cols; W from global (L2-hot)
// ---------------------------------------------------------------------------
__global__ __launch_bounds__(256) void input_proj_kernel(const float* __restrict__ x,
                                                         const float* __restrict__ W,
                                                         const float* __restrict__ b,
                                                         float* __restrict__ hbuf) {
    int t = threadIdx.x, wave = t >> 6, lane = t & 63;
    int n = blockIdx.x * 4 + wave;  // grid = N/4 exactly
    float xown = (lane < NODE_IN) ? x[(size_t)n * NODE_IN + lane] : 0.f;
    int c0 = lane * 2, c1 = c0 + 1;
    float a0 = b[c0], a1 = b[c1];
#pragma unroll
    for (int k = 0; k < NODE_IN; k++) {
        float xv = __shfl(xown, k, 64);
        a0 += xv * W[k * EMB + c0];
        a1 += xv * W[k * EMB + c1];
    }
    hbuf[(size_t)n * EMB + c0] = fmaxf(a0, 0.f);
    hbuf[(size_t)n * EMB + c1] = fmaxf(a1, 0.f);
}

// ---------------------------------------------------------------------------
// xs = [x|h] @ W_src[l]; a_s/a_d per-head attention dots.
// wave per node, lane = 2 cols; W from global (80KB, L2-hot), input row in LDS.
// ---------------------------------------------------------------------------
__global__ __launch_bounds__(256) void xs_kernel(const float* __restrict__ x,
                                                 const float* __restrict__ hbuf,
                                                 const float* __restrict__ Wsrc_l,
                                                 const float* __restrict__ attS_l,
                                                 const float* __restrict__ attD_l,
                                                 float* __restrict__ xs,
                                                 float* __restrict__ a_s,
                                                 float* __restrict__ a_d) {
    __shared__ float inp[4][GAT_IN];  // 2.56 KB
    int t = threadIdx.x, wave = t >> 6, lane = t & 63;
    int n = blockIdx.x * 4 + wave;  // grid = N/4 exactly
    if (lane < NODE_IN) inp[wave][lane] = x[(size_t)n * NODE_IN + lane];
    inp[wave][NODE_IN + lane]      = hbuf[(size_t)n * EMB + lane];
    inp[wave][NODE_IN + 64 + lane] = hbuf[(size_t)n * EMB + 64 + lane];
    __syncthreads();
    int c0 = lane * 2, c1 = c0 + 1;
    float a0 = 0.f, a1 = 0.f;
#pragma unroll 8
    for (int k = 0; k < GAT_IN; k++) {
        float v = inp[wave][k];
        a0 += v * Wsrc_l[k * EMB + c0];
        a1 += v * Wsrc_l[k * EMB + c1];
    }
    xs[(size_t)n * EMB + c0] = a0;
    xs[(size_t)n * EMB + c1] = a1;
    float ps = a0 * attS_l[c0] + a1 * attS_l[c1];
    float pd = a0 * attD_l[c0] + a1 * attD_l[c1];
#pragma unroll
    for (int off = 8; off >= 1; off >>= 1) {
        ps += __shfl_down(ps, off, 16);
        pd += __shfl_down(pd, off, 16);
    }
    if ((lane & 15) == 0) {
        int h = lane >> 4;
        a_s[(size_t)n * 4 + h] = ps;
        a_d[(size_t)n * 4 + h] = pd;
    }
}

// ---------------------------------------------------------------------------
// fused edge pass: ex = exp(lrelu(a_s[src]+a_d[dst]+a_e)); atomic denom;
// atomic scatter of UNNORMALIZED ex*xs[src] (normalize later per node).
// No max-shift: |alpha| is O(1) here; softmax is shift-invariant.
// phase 1: thread/edge.  phase 2: 32 threads/edge.
// ---------------------------------------------------------------------------
__global__ __launch_bounds__(256) void edge_fused_kernel(const int* __restrict__ edge_index,
                                                         const float* __restrict__ edge_attr,
                                                         const float* __restrict__ a_s,
                                                         const float* __restrict__ a_d,
                                                         const float* __restrict__ meta,
                                                         int layer,
                                                         const float* __restrict__ xs,
                                                         float* __restrict__ denom,
                                                         float* __restrict__ out_acc) {
    __shared__ float Ml[64];
    __shared__ float loop_ae[4];
    __shared__ float exs[256][4];  // 4 KB
    __shared__ int srcs[256];
    __shared__ int dsts[256];
    int t = threadIdx.x;
    if (t < 64) Ml[t] = meta[16 + layer * 64 + t];
    if (t < 4) loop_ae[t] = meta[144 + layer * 4 + t];
    __syncthreads();
    int e0 = blockIdx.x * 256;
    int e = e0 + t;
    if (e < E2) {
        int src, dst;
        float ae[4];
        if (e < N_EDGES) {
            src = edge_index[e];
            dst = edge_index[N_EDGES + e];
            const float* row = edge_attr + (size_t)e * EDGE_IN;
            float eav[EDGE_IN];
#pragma unroll
            for (int k = 0; k < EDGE_IN; k++) eav[k] = row[k];
#pragma unroll
            for (int h = 0; h < 4; h++) {
                float acc = 0.f;
#pragma unroll
                for (int k = 0; k < EDGE_IN; k++) acc += eav[k] * Ml[k * 4 + h];
                ae[h] = acc;
            }
        } else {
            src = dst = e - N_EDGES;
#pragma unroll
            for (int h = 0; h < 4; h++) ae[h] = loop_ae[h];
        }
        srcs[t] = src;
        dsts[t] = dst;
#pragma unroll
        for (int h = 0; h < 4; h++) {
            float a = a_s[(size_t)src * 4 + h] + a_d[(size_t)dst * 4 + h] + ae[h];
            a = a > 0.f ? a : 0.2f * a;   // leaky relu
            float ex = __expf(a);
            exs[t][h] = ex;
            atomicAdd(&denom[(size_t)dst * 4 + h], ex);
        }
    }
    __syncthreads();
    int l32 = t & 31, h = l32 >> 3;
#pragma unroll 4
    for (int i = 0; i < 32; i++) {
        int el = (t >> 5) + i * 8;
        int ee = e0 + el;
        if (ee < E2) {
            float w = exs[el][h];
            int s = srcs[el], d = dsts[el];
            const float* v = xs + (size_t)s * EMB + l32 * 4;
            float* o = out_acc + (size_t)d * EMB + l32 * 4;
            atomicAdd(o + 0, v[0] * w);
            atomicAdd(o + 1, v[1] * w);
            atomicAdd(o + 2, v[2] * w);
            atomicAdd(o + 3, v[3] * w);
        }
    }
}

// ---------------------------------------------------------------------------
// h = elu(layernorm(out_acc/denom + gat_bias)); wave per node
// ---------------------------------------------------------------------------
__global__ __launch_bounds__(256) void node_update_kernel(const float* __restrict__ out_acc,
                                                          const float* __restrict__ denom,
                                                          const float* __restrict__ bias_l,
                                                          const float* __restrict__ gamma_l,
                                                          const float* __restrict__ beta_l,
                                                          float* __restrict__ hbuf) {
    int t = threadIdx.x, wave = t >> 6, lane = t & 63;
    int n = blockIdx.x * 4 + wave;  // grid = N/4 exactly
    int c0 = lane * 2, c1 = c0 + 1;
    int h = lane >> 4;  // both cols in same 32-wide head block
    float dinv = 1.0f / (denom[(size_t)n * 4 + h] + 1e-16f);
    float v0 = out_acc[(size_t)n * EMB + c0] * dinv + bias_l[c0];
    float v1 = out_acc[(size_t)n * EMB + c1] * dinv + bias_l[c1];
    float s = v0 + v1, sq = v0 * v0 + v1 * v1;
#pragma unroll
    for (int off = 32; off >= 1; off >>= 1) {
        s += __shfl_down(s, off, 64);
        sq += __shfl_down(sq, off, 64);
    }
    s = __shfl(s, 0, 64);
    sq = __shfl(sq, 0, 64);
    float mean = s * (1.f / EMB);
    float var = sq * (1.f / EMB) - mean * mean;
    float rstd = rsqrtf(var + 1e-5f);
    float y0 = (v0 - mean) * rstd * gamma_l[c0] + beta_l[c0];
    float y1 = (v1 - mean) * rstd * gamma_l[c1] + beta_l[c1];
    y0 = y0 > 0.f ? y0 : __expf(y0) - 1.f;  // elu
    y1 = y1 > 0.f ? y1 : __expf(y1) - 1.f;
    hbuf[(size_t)n * EMB + c0] = y0;
    hbuf[(size_t)n * EMB + c1] = y1;
}

// ---------------------------------------------------------------------------
// node head: out = LN(relu(h@W_out+b_out)); W from global (64KB, L2-hot)
// ---------------------------------------------------------------------------
__global__ __launch_bounds__(256) void node_head_kernel(const float* __restrict__ hbuf,
                                                        const float* __restrict__ W,
                                                        const float* __restrict__ b,
                                                        const float* __restrict__ lng,
                                                        const float* __restrict__ lnb,
                                                        float* __restrict__ out_nodes) {
    __shared__ float hrow[4][EMB];  // 2 KB
    int t = threadIdx.x, wave = t >> 6, lane = t & 63;
    int n = blockIdx.x * 4 + wave;  // grid = N/4 exactly
    hrow[wave][lane]      = hbuf[(size_t)n * EMB + lane];
    hrow[wave][64 + lane] = hbuf[(size_t)n * EMB + 64 + lane];
    __syncthreads();
    int c0 = lane * 2, c1 = c0 + 1;
    float o0 = b[c0], o1 = b[c1];
#pragma unroll 8
    for (int k = 0; k < EMB; k++) {
        float v = hrow[wave][k];
        o0 += v * W[k * EMB + c0];
        o1 += v * W[k * EMB + c1];
    }
    o0 = fmaxf(o0, 0.f); o1 = fmaxf(o1, 0.f);
    float s = o0 + o1, sq = o0 * o0 + o1 * o1;
#pragma unroll
    for (int off = 32; off >= 1; off >>= 1) {
        s += __shfl_down(s, off, 64);
        sq += __shfl_down(sq, off, 64);
    }
    s = __shfl(s, 0, 64); sq = __shfl(sq, 0, 64);
    float m = s * (1.f / EMB), v = sq * (1.f / EMB) - m * m;
    float r = rsqrtf(v + 1e-5f);
    out_nodes[(size_t)n * EMB + c0] = (o0 - m) * r * lng[c0] + lnb[c0];
    out_nodes[(size_t)n * EMB + c1] = (o1 - m) * r * lng[c1] + lnb[c1];
}

// ---------------------------------------------------------------------------
// graph head: g = LN(relu(h@W_g+b_g)); pooled sums via atomics
// ---------------------------------------------------------------------------
__global__ __launch_bounds__(256) void graph_head_kernel(const float* __restrict__ hbuf,
                                                         const float* __restrict__ W,
                                                         const float* __restrict__ b,
                                                         const float* __restrict__ gg,
                                                         const float* __restrict__ gb,
                                                         const int* __restrict__ batch,
                                                         float* __restrict__ gsum,
                                                         float* __restrict__ gcnt) {
    __shared__ float hrow[4][EMB];  // 2 KB
    int t = threadIdx.x, wave = t >> 6, lane = t & 63;
    int n = blockIdx.x * 4 + wave;  // grid = N/4 exactly
    hrow[wave][lane]      = hbuf[(size_t)n * EMB + lane];
    hrow[wave][64 + lane] = hbuf[(size_t)n * EMB + 64 + lane];
    __syncthreads();
    int c0 = lane * 2, c1 = c0 + 1;
    float g0 = b[c0], g1 = b[c1];
#pragma unroll 8
    for (int k = 0; k < EMB; k++) {
        float v = hrow[wave][k];
        g0 += v * W[k * EMB + c0];
        g1 += v * W[k * EMB + c1];
    }
    g0 = fmaxf(g0, 0.f); g1 = fmaxf(g1, 0.f);
    float s = g0 + g1, sq = g0 * g0 + g1 * g1;
#pragma unroll
    for (int off = 32; off >= 1; off >>= 1) {
        s += __shfl_down(s, off, 64);
        sq += __shfl_down(sq, off, 64);
    }
    s = __shfl(s, 0, 64); sq = __shfl(sq, 0, 64);
    float m = s * (1.f / EMB), v = sq * (1.f / EMB) - m * m;
    float r = rsqrtf(v + 1e-5f);
    float z0 = (g0 - m) * r * gg[c0] + gb[c0];
    float z1 = (g1 - m) * r * gg[c1] + gb[c1];
    int bb = batch[n];
    atomicAdd(&gsum[(size_t)bb * EMB + c0], z0);
    atomicAdd(&gsum[(size_t)bb * EMB + c1], z1);
    if (lane == 0) atomicAdd(&gcnt[bb], 1.f);
}

__global__ void graph_out_kernel(const float* __restrict__ gsum, const float* __restrict__ gcnt,
                                 float* __restrict__ out) {
    int i = blockIdx.x * blockDim.x + threadIdx.x;
    if (i >= NGRAPH * EMB) return;
    int b = i >> 7;
    float c = fmaxf(gcnt[b], 1.f);
    out[(size_t)N_NODES * EMB + i] = gsum[i] / c;
}

// ---------------------------------------------------------------------------
extern "C" void kernel_launch(void* const* d_in, const int* in_sizes, int n_in,
                              void* d_out, int out_size, void* d_ws, size_t ws_size,
                              hipStream_t stream) {
    (void)in_sizes; (void)n_in; (void)out_size; (void)ws_size;
    const float* x         = (const float*)d_in[0];
    const float* edge_attr = (const float*)d_in[1];
    const float* W_in      = (const float*)d_in[2];
    const float* b_in      = (const float*)d_in[3];
    const float* W_src     = (const float*)d_in[4];
    const float* W_edge    = (const float*)d_in[5];
    const float* att_src   = (const float*)d_in[6];
    const float* att_dst   = (const float*)d_in[7];
    const float* att_edge  = (const float*)d_in[8];
    const float* gat_bias  = (const float*)d_in[9];
    const float* ln_gamma  = (const float*)d_in[10];
    const float* ln_beta   = (const float*)d_in[11];
    const float* W_out     = (const float*)d_in[12];
    const float* b_out     = (const float*)d_in[13];
    const float* ln_og     = (const float*)d_in[14];
    const float* ln_ob     = (const float*)d_in[15];
    const float* W_g       = (const float*)d_in[16];
    const float* b_g       = (const float*)d_in[17];
    const float* g_gamma   = (const float*)d_in[18];
    const float* g_beta    = (const float*)d_in[19];
    const int* edge_index  = (const int*)d_in[20];
    const int* batch       = (const int*)d_in[21];
    float* out = (float*)d_out;

    float* ws     = (float*)d_ws;
    float* h_buf  = ws;                                  // N*128
    float* xs     = h_buf + (size_t)N_NODES * EMB;       // N*128
    float* outacc = xs + (size_t)N_NODES * EMB;          // N*128
    float* a_s    = outacc + (size_t)N_NODES * EMB;      // N*4
    float* a_d    = a_s + (size_t)N_NODES * 4;           // N*4
    float* denom  = a_d + (size_t)N_NODES * 4;           // N*4
    float* meta   = denom + (size_t)N_NODES * 4;         // 152
    float* gsum   = meta + 152;                          // 8*128
    float* gcnt   = gsum + NGRAPH * EMB;                 // 8
    // total ~19.8M floats = 79.3 MB

    // zero meta+gsum+gcnt (contiguous 1184 floats)
    zero_kernel<<<8, 256, 0, stream>>>(meta, 152 + NGRAPH * EMB + NGRAPH);
    mean_ea_kernel<<<256, 256, 0, stream>>>(edge_attr, meta);
    prep_kernel<<<1, 128, 0, stream>>>(W_edge, att_edge, meta);
    input_proj_kernel<<<N_NODES / 4, 256, 0, stream>>>(x, W_in, b_in, h_buf);

    for (int l = 0; l < NLAYER; l++) {
        xs_kernel<<<N_NODES / 4, 256, 0, stream>>>(
            x, h_buf, W_src + (size_t)l * GAT_IN * EMB,
            att_src + (size_t)l * EMB, att_dst + (size_t)l * EMB, xs, a_s, a_d);
        zero_kernel<<<784, 256, 0, stream>>>(denom, N_NODES * 4);
        zero_kernel<<<4096, 256, 0, stream>>>(outacc, N_NODES * EMB);
        edge_fused_kernel<<<(E2 + 255) / 256, 256, 0, stream>>>(
            edge_index, edge_attr, a_s, a_d, meta, l, xs, denom, outacc);
        node_update_kernel<<<N_NODES / 4, 256, 0, stream>>>(
            outacc, denom, gat_bias + (size_t)l * EMB, ln_gamma + (size_t)l * EMB,
            ln_beta + (size_t)l * EMB, h_buf);
    }

    node_head_kernel<<<N_NODES / 4, 256, 0, stream>>>(h_buf, W_out, b_out, ln_og, ln_ob, out);
    graph_head_kernel<<<N_NODES / 4, 256, 0, stream>>>(h_buf, W_g, b_g, g_gamma, g_beta,
                                                       batch, gsum, gcnt);
    graph_out_kernel<<<4, 256, 0, stream>>>(gsum, gcnt, out);
}

// Round 4
// 921.208 us; speedup vs baseline: 5.5121x; 5.5121x over previous
//
#include <hip/hip_runtime.h>

#define N_NODES 50000
#define N_EDGES 800000
#define E2      850000        // N_EDGES + N_NODES (self loops)
#define NODE_IN 32
#define EDGE_IN 16
#define EMB     128
#define GAT_IN  160           // NODE_IN + EMB
#define NLAYER  2
#define NGRAPH  8

// ---------------------------------------------------------------------------
// zero fill (graph-capture safe); also used to zero int buffers via cast
// ---------------------------------------------------------------------------
__global__ void zero_kernel(float* __restrict__ p, int n) {
    int i = blockIdx.x * blockDim.x + threadIdx.x;
    int stride = gridDim.x * blockDim.x;
    for (; i < n; i += stride) p[i] = 0.f;
}

// ---------------------------------------------------------------------------
// mean of edge_attr over E edges -> meta[0..16) as sums (divided in prep)
// ---------------------------------------------------------------------------
__global__ __launch_bounds__(256) void mean_ea_kernel(const float* __restrict__ ea,
                                                      float* __restrict__ meta) {
    __shared__ float sm[EDGE_IN];
    int t = threadIdx.x;
    if (t < EDGE_IN) sm[t] = 0.f;
    __syncthreads();
    float s[EDGE_IN];
#pragma unroll
    for (int k = 0; k < EDGE_IN; k++) s[k] = 0.f;
    for (int e = blockIdx.x * blockDim.x + t; e < N_EDGES; e += gridDim.x * blockDim.x) {
        const float* row = ea + (size_t)e * EDGE_IN;
#pragma unroll
        for (int k = 0; k < EDGE_IN; k++) s[k] += row[k];
    }
#pragma unroll
    for (int k = 0; k < EDGE_IN; k++) atomicAdd(&sm[k], s[k]);
    __syncthreads();
    if (t < EDGE_IN) atomicAdd(&meta[t], sm[t]);
}

// ---------------------------------------------------------------------------
// prep: finish mean; M[l][k][h]=sum_c W_edge[l,k,h*32+c]*att_edge[l,h,c]
// -> meta[16..144); self-loop a_e[l][h] -> meta[144..152)
// ---------------------------------------------------------------------------
__global__ void prep_kernel(const float* __restrict__ W_edge,
                            const float* __restrict__ att_edge,
                            float* __restrict__ meta) {
    int t = threadIdx.x;  // 128 threads
    if (t < EDGE_IN) meta[t] = meta[t] * (1.0f / (float)N_EDGES);
    __syncthreads();
    {
        int l = t >> 6, k = (t >> 2) & 15, h = t & 3;
        const float* w = W_edge + ((size_t)l * EDGE_IN + k) * EMB + h * 32;
        const float* a = att_edge + (size_t)l * EMB + h * 32;
        float acc = 0.f;
#pragma unroll
        for (int c = 0; c < 32; c++) acc += w[c] * a[c];
        meta[16 + (l * 16 + k) * 4 + h] = acc;
    }
    __syncthreads();
    if (t < 8) {
        int l = t >> 2, h = t & 3;
        float acc = 0.f;
#pragma unroll
        for (int k = 0; k < EDGE_IN; k++) acc += meta[k] * meta[16 + (l * 16 + k) * 4 + h];
        meta[144 + t] = acc;
    }
}

// ---------------------------------------------------------------------------
// CSR build: count incoming edges per dst
// ---------------------------------------------------------------------------
__global__ __launch_bounds__(256) void count_kernel(const int* __restrict__ edge_index,
                                                    int* __restrict__ cnt) {
    int e = blockIdx.x * 256 + threadIdx.x;
    if (e >= E2) return;
    int dst = (e < N_EDGES) ? edge_index[N_EDGES + e] : (e - N_EDGES);
    atomicAdd(&cnt[dst], 1);
}

// single-block exclusive scan of cnt[N] -> off[N+1]; also copy into cursor
__global__ __launch_bounds__(256) void scan_kernel(const int* __restrict__ cnt,
                                                   int* __restrict__ off,
                                                   int* __restrict__ cursor) {
    __shared__ int part[256];
    int t = threadIdx.x;
    const int CHUNK = (N_NODES + 255) / 256;  // 196
    int start = t * CHUNK;
    int end = min(start + CHUNK, N_NODES);
    int local = 0;
    for (int i = start; i < end; i++) local += cnt[i];
    part[t] = local;
    __syncthreads();
    for (int d = 1; d < 256; d <<= 1) {
        int v = (t >= d) ? part[t - d] : 0;
        __syncthreads();
        part[t] += v;
        __syncthreads();
    }
    int run = (t == 0) ? 0 : part[t - 1];
    for (int i = start; i < end; i++) {
        off[i] = run;
        cursor[i] = run;
        run += cnt[i];
    }
    if (t == 0) off[N_NODES] = E2;
}

// fill: csr_src[pos] = src of each incoming edge (dst-grouped); csr_pos[e] = pos
__global__ __launch_bounds__(256) void fill_kernel(const int* __restrict__ edge_index,
                                                   int* __restrict__ cursor,
                                                   int* __restrict__ csr_src,
                                                   int* __restrict__ csr_pos) {
    int e = blockIdx.x * 256 + threadIdx.x;
    if (e >= E2) return;
    int src, dst;
    if (e < N_EDGES) {
        src = edge_index[e];
        dst = edge_index[N_EDGES + e];
    } else {
        src = dst = e - N_EDGES;
    }
    int pos = atomicAdd(&cursor[dst], 1);
    csr_src[pos] = src;
    csr_pos[e] = pos;
}

// ---------------------------------------------------------------------------
// per-layer: write a_e (4 heads) for each edge into CSR order
// ---------------------------------------------------------------------------
__global__ __launch_bounds__(256) void ae_fill_kernel(const float* __restrict__ edge_attr,
                                                      const float* __restrict__ meta,
                                                      int layer,
                                                      const int* __restrict__ csr_pos,
                                                      float* __restrict__ csr_ae) {
    __shared__ float Ml[64];
    __shared__ float loop_ae[4];
    int t = threadIdx.x;
    if (t < 64) Ml[t] = meta[16 + layer * 64 + t];
    if (t < 4) loop_ae[t] = meta[144 + layer * 4 + t];
    __syncthreads();
    int e = blockIdx.x * 256 + t;
    if (e >= E2) return;
    float ae[4];
    if (e < N_EDGES) {
        const float4* r4 = (const float4*)(edge_attr + (size_t)e * EDGE_IN);
#pragma unroll
        for (int h = 0; h < 4; h++) ae[h] = 0.f;
#pragma unroll
        for (int q = 0; q < 4; q++) {
            float4 v = r4[q];
#pragma unroll
            for (int h = 0; h < 4; h++) {
                ae[h] += v.x * Ml[(4 * q + 0) * 4 + h] + v.y * Ml[(4 * q + 1) * 4 + h] +
                         v.z * Ml[(4 * q + 2) * 4 + h] + v.w * Ml[(4 * q + 3) * 4 + h];
            }
        }
    } else {
#pragma unroll
        for (int h = 0; h < 4; h++) ae[h] = loop_ae[h];
    }
    ((float4*)csr_ae)[csr_pos[e]] = make_float4(ae[0], ae[1], ae[2], ae[3]);
}

// ---------------------------------------------------------------------------
// GEMV pattern: 16 nodes/block (4 per wave), lane = 2 cols, float2 W loads
// ---------------------------------------------------------------------------
// h = relu(x @ W_in + b_in)
__global__ __launch_bounds__(256) void input_proj_kernel(const float* __restrict__ x,
                                                         const float* __restrict__ W,
                                                         const float* __restrict__ b,
                                                         float* __restrict__ hbuf) {
    __shared__ float inp[16][NODE_IN];  // 2 KB
    int t = threadIdx.x;
    int n0 = blockIdx.x * 16;
    for (int i = t; i < 16 * NODE_IN; i += 256) {
        int r = i >> 5, c = i & 31;
        inp[r][c] = x[(size_t)(n0 + r) * NODE_IN + c];
    }
    __syncthreads();
    int wave = t >> 6, lane = t & 63;
    int c0 = lane * 2, c1 = c0 + 1;
    const float2* W2 = (const float2*)W;
    float acc[4][2];
#pragma unroll
    for (int j = 0; j < 4; j++) { acc[j][0] = b[c0]; acc[j][1] = b[c1]; }
#pragma unroll 8
    for (int k = 0; k < NODE_IN; k++) {
        float2 w = W2[k * 64 + lane];
#pragma unroll
        for (int j = 0; j < 4; j++) {
            float v = inp[wave * 4 + j][k];
            acc[j][0] += v * w.x;
            acc[j][1] += v * w.y;
        }
    }
    float2* out2 = (float2*)hbuf;
#pragma unroll
    for (int j = 0; j < 4; j++) {
        int n = n0 + wave * 4 + j;
        out2[(size_t)n * 64 + lane] = make_float2(fmaxf(acc[j][0], 0.f), fmaxf(acc[j][1], 0.f));
    }
}

// xs = [x|h] @ W_src[l]; a_s/a_d per-head dots
__global__ __launch_bounds__(256) void xs_kernel(const float* __restrict__ x,
                                                 const float* __restrict__ hbuf,
                                                 const float* __restrict__ Wsrc_l,
                                                 const float* __restrict__ attS_l,
                                                 const float* __restrict__ attD_l,
                                                 float* __restrict__ xs,
                                                 float* __restrict__ a_s,
                                                 float* __restrict__ a_d) {
    __shared__ float inp[16][GAT_IN];  // 10.24 KB
    int t = threadIdx.x;
    int n0 = blockIdx.x * 16;
    for (int i = t; i < 16 * GAT_IN; i += 256) {
        int r = i / GAT_IN, c = i - r * GAT_IN;
        int n = n0 + r;
        inp[r][c] = (c < NODE_IN) ? x[(size_t)n * NODE_IN + c]
                                  : hbuf[(size_t)n * EMB + (c - NODE_IN)];
    }
    __syncthreads();
    int wave = t >> 6, lane = t & 63;
    int c0 = lane * 2, c1 = c0 + 1;
    const float2* W2 = (const float2*)Wsrc_l;
    float acc[4][2];
#pragma unroll
    for (int j = 0; j < 4; j++) acc[j][0] = acc[j][1] = 0.f;
#pragma unroll 8
    for (int k = 0; k < GAT_IN; k++) {
        float2 w = W2[k * 64 + lane];
#pragma unroll
        for (int j = 0; j < 4; j++) {
            float v = inp[wave * 4 + j][k];
            acc[j][0] += v * w.x;
            acc[j][1] += v * w.y;
        }
    }
    float sA = attS_l[c0], sB = attS_l[c1];
    float dA = attD_l[c0], dB = attD_l[c1];
    float2* xs2 = (float2*)xs;
#pragma unroll
    for (int j = 0; j < 4; j++) {
        int n = n0 + wave * 4 + j;
        xs2[(size_t)n * 64 + lane] = make_float2(acc[j][0], acc[j][1]);
        float ps = acc[j][0] * sA + acc[j][1] * sB;
        float pd = acc[j][0] * dA + acc[j][1] * dB;
#pragma unroll
        for (int off = 8; off >= 1; off >>= 1) {
            ps += __shfl_down(ps, off, 16);
            pd += __shfl_down(pd, off, 16);
        }
        if ((lane & 15) == 0) {
            int h = lane >> 4;
            a_s[(size_t)n * 4 + h] = ps;
            a_d[(size_t)n * 4 + h] = pd;
        }
    }
}

// ---------------------------------------------------------------------------
// gather: wave per node; walk CSR incoming edges; softmax-weighted sum of
// xs[src]; fused /denom + bias + LN + ELU epilogue. ZERO atomics.
// ---------------------------------------------------------------------------
__global__ __launch_bounds__(256) void gat_gather_kernel(const int* __restrict__ off,
                                                         const int* __restrict__ csr_src,
                                                         const float* __restrict__ csr_ae,
                                                         const float* __restrict__ xs,
                                                         const float* __restrict__ a_s,
                                                         const float* __restrict__ a_d,
                                                         const float* __restrict__ bias_l,
                                                         const float* __restrict__ gamma_l,
                                                         const float* __restrict__ beta_l,
                                                         float* __restrict__ hbuf) {
    int t = threadIdx.x, wave = t >> 6, lane = t & 63;
    int n = blockIdx.x * 4 + wave;  // grid = N/4 exactly
    int c0 = lane * 2, c1 = c0 + 1;
    int h = lane >> 4;
    float ad = a_d[(size_t)n * 4 + h];
    int p0 = off[n], p1 = off[n + 1];
    const float2* xs2 = (const float2*)xs;
    float den = 0.f, acc0 = 0.f, acc1 = 0.f;
    int s = csr_src[p0];  // every node has >=1 edge (self loop)
    for (int p = p0; p < p1; p++) {
        int s_next = (p + 1 < p1) ? csr_src[p + 1] : 0;
        float ae = csr_ae[(size_t)p * 4 + h];
        float as = a_s[(size_t)s * 4 + h];
        float2 v = xs2[(size_t)s * 64 + lane];
        float al = as + ad + ae;
        al = al > 0.f ? al : 0.2f * al;  // leaky relu
        float ex = __expf(al);           // no max-shift: |alpha| O(1)
        den += ex;
        acc0 += ex * v.x;
        acc1 += ex * v.y;
        s = s_next;
    }
    float dinv = 1.0f / (den + 1e-16f);
    float v0 = acc0 * dinv + bias_l[c0];
    float v1 = acc1 * dinv + bias_l[c1];
    float sm = v0 + v1, sq = v0 * v0 + v1 * v1;
#pragma unroll
    for (int o = 32; o >= 1; o >>= 1) {
        sm += __shfl_down(sm, o, 64);
        sq += __shfl_down(sq, o, 64);
    }
    sm = __shfl(sm, 0, 64);
    sq = __shfl(sq, 0, 64);
    float mean = sm * (1.f / EMB);
    float var = sq * (1.f / EMB) - mean * mean;
    float rstd = rsqrtf(var + 1e-5f);
    float y0 = (v0 - mean) * rstd * gamma_l[c0] + beta_l[c0];
    float y1 = (v1 - mean) * rstd * gamma_l[c1] + beta_l[c1];
    y0 = y0 > 0.f ? y0 : __expf(y0) - 1.f;  // elu
    y1 = y1 > 0.f ? y1 : __expf(y1) - 1.f;
    float2* out2 = (float2*)hbuf;
    out2[(size_t)n * 64 + lane] = make_float2(y0, y1);
}

// ---------------------------------------------------------------------------
// node head: out = LN(relu(h@W_out+b_out)); 16 nodes/block
// ---------------------------------------------------------------------------
__global__ __launch_bounds__(256) void node_head_kernel(const float* __restrict__ hbuf,
                                                        const float* __restrict__ W,
                                                        const float* __restrict__ b,
                                                        const float* __restrict__ lng,
                                                        const float* __restrict__ lnb,
                                                        float* __restrict__ out_nodes) {
    __shared__ float inp[16][EMB];  // 8 KB
    int t = threadIdx.x;
    int n0 = blockIdx.x * 16;
    for (int i = t; i < 16 * EMB; i += 256) {
        int r = i >> 7, c = i & 127;
        inp[r][c] = hbuf[(size_t)(n0 + r) * EMB + c];
    }
    __syncthreads();
    int wave = t >> 6, lane = t & 63;
    int c0 = lane * 2, c1 = c0 + 1;
    const float2* W2 = (const float2*)W;
    float acc[4][2];
#pragma unroll
    for (int j = 0; j < 4; j++) { acc[j][0] = b[c0]; acc[j][1] = b[c1]; }
#pragma unroll 8
    for (int k = 0; k < EMB; k++) {
        float2 w = W2[k * 64 + lane];
#pragma unroll
        for (int j = 0; j < 4; j++) {
            float v = inp[wave * 4 + j][k];
            acc[j][0] += v * w.x;
            acc[j][1] += v * w.y;
        }
    }
    float gA = lng[c0], gB = lng[c1], bA = lnb[c0], bB = lnb[c1];
    float2* out2 = (float2*)out_nodes;
#pragma unroll
    for (int j = 0; j < 4; j++) {
        int n = n0 + wave * 4 + j;
        float o0 = fmaxf(acc[j][0], 0.f), o1 = fmaxf(acc[j][1], 0.f);
        float sm = o0 + o1, sq = o0 * o0 + o1 * o1;
#pragma unroll
        for (int o = 32; o >= 1; o >>= 1) {
            sm += __shfl_down(sm, o, 64);
            sq += __shfl_down(sq, o, 64);
        }
        sm = __shfl(sm, 0, 64);
        sq = __shfl(sq, 0, 64);
        float m = sm * (1.f / EMB), v = sq * (1.f / EMB) - m * m;
        float r = rsqrtf(v + 1e-5f);
        out2[(size_t)n * 64 + lane] =
            make_float2((o0 - m) * r * gA + bA, (o1 - m) * r * gB + bB);
    }
}

// ---------------------------------------------------------------------------
// graph head: g = LN(relu(h@W_g+b_g)); LDS-local pooling (8 graphs total)
// ---------------------------------------------------------------------------
__global__ __launch_bounds__(256) void graph_head_kernel(const float* __restrict__ hbuf,
                                                         const float* __restrict__ W,
                                                         const float* __restrict__ b,
                                                         const float* __restrict__ gg,
                                                         const float* __restrict__ gb,
                                                         const int* __restrict__ batch,
                                                         float* __restrict__ gsum,
                                                         float* __restrict__ gcnt) {
    __shared__ float inp[16][EMB];       // 8 KB
    __shared__ float loc[NGRAPH][EMB];   // 4 KB
    __shared__ int cnts[NGRAPH];
    __shared__ int bids[16];
    int t = threadIdx.x;
    int n0 = blockIdx.x * 16;
    for (int i = t; i < 16 * EMB; i += 256) {
        int r = i >> 7, c = i & 127;
        inp[r][c] = hbuf[(size_t)(n0 + r) * EMB + c];
    }
    for (int i = t; i < NGRAPH * EMB; i += 256) ((float*)loc)[i] = 0.f;
    if (t < NGRAPH) cnts[t] = 0;
    if (t < 16) bids[t] = batch[n0 + t];
    __syncthreads();
    int wave = t >> 6, lane = t & 63;
    int c0 = lane * 2, c1 = c0 + 1;
    const float2* W2 = (const float2*)W;
    float acc[4][2];
#pragma unroll
    for (int j = 0; j < 4; j++) { acc[j][0] = b[c0]; acc[j][1] = b[c1]; }
#pragma unroll 8
    for (int k = 0; k < EMB; k++) {
        float2 w = W2[k * 64 + lane];
#pragma unroll
        for (int j = 0; j < 4; j++) {
            float v = inp[wave * 4 + j][k];
            acc[j][0] += v * w.x;
            acc[j][1] += v * w.y;
        }
    }
    float gA = gg[c0], gB = gg[c1], bA = gb[c0], bB = gb[c1];
#pragma unroll
    for (int j = 0; j < 4; j++) {
        int r = wave * 4 + j;
        float o0 = fmaxf(acc[j][0], 0.f), o1 = fmaxf(acc[j][1], 0.f);
        float sm = o0 + o1, sq = o0 * o0 + o1 * o1;
#pragma unroll
        for (int o = 32; o >= 1; o >>= 1) {
            sm += __shfl_down(sm, o, 64);
            sq += __shfl_down(sq, o, 64);
        }
        sm = __shfl(sm, 0, 64);
        sq = __shfl(sq, 0, 64);
        float m = sm * (1.f / EMB), v = sq * (1.f / EMB) - m * m;
        float rs = rsqrtf(v + 1e-5f);
        float z0 = (o0 - m) * rs * gA + bA;
        float z1 = (o1 - m) * rs * gB + bB;
        int bb = bids[r];
        atomicAdd(&loc[bb][c0], z0);
        atomicAdd(&loc[bb][c1], z1);
        if (lane == 0) atomicAdd(&cnts[bb], 1);
    }
    __syncthreads();
    // flush: only graphs present in this block's node range [bids[0], bids[15]]
    int bmin = bids[0], bmax = bids[15];
    int span = (bmax - bmin + 1) * EMB;
    for (int i = t; i < span; i += 256) {
        int g = bmin + (i >> 7), c = i & 127;
        atomicAdd(&gsum[(size_t)g * EMB + c], loc[g][c]);
    }
    if (t >= bmin && t <= bmax && cnts[t] > 0) atomicAdd(&gcnt[t], (float)cnts[t]);
}

__global__ void graph_out_kernel(const float* __restrict__ gsum, const float* __restrict__ gcnt,
                                 float* __restrict__ out) {
    int i = blockIdx.x * blockDim.x + threadIdx.x;
    if (i >= NGRAPH * EMB) return;
    int b = i >> 7;
    float c = fmaxf(gcnt[b], 1.f);
    out[(size_t)N_NODES * EMB + i] = gsum[i] / c;
}

// ---------------------------------------------------------------------------
extern "C" void kernel_launch(void* const* d_in, const int* in_sizes, int n_in,
                              void* d_out, int out_size, void* d_ws, size_t ws_size,
                              hipStream_t stream) {
    (void)in_sizes; (void)n_in; (void)out_size; (void)ws_size;
    const float* x         = (const float*)d_in[0];
    const float* edge_attr = (const float*)d_in[1];
    const float* W_in      = (const float*)d_in[2];
    const float* b_in      = (const float*)d_in[3];
    const float* W_src     = (const float*)d_in[4];
    const float* W_edge    = (const float*)d_in[5];
    const float* att_src   = (const float*)d_in[6];
    const float* att_dst   = (const float*)d_in[7];
    const float* att_edge  = (const float*)d_in[8];
    const float* gat_bias  = (const float*)d_in[9];
    const float* ln_gamma  = (const float*)d_in[10];
    const float* ln_beta   = (const float*)d_in[11];
    const float* W_out     = (const float*)d_in[12];
    const float* b_out     = (const float*)d_in[13];
    const float* ln_og     = (const float*)d_in[14];
    const float* ln_ob     = (const float*)d_in[15];
    const float* W_g       = (const float*)d_in[16];
    const float* b_g       = (const float*)d_in[17];
    const float* g_gamma   = (const float*)d_in[18];
    const float* g_beta    = (const float*)d_in[19];
    const int* edge_index  = (const int*)d_in[20];
    const int* batch       = (const int*)d_in[21];
    float* out = (float*)d_out;

    float* ws     = (float*)d_ws;
    float* h_buf  = ws;                                  // N*128
    float* xs     = h_buf + (size_t)N_NODES * EMB;       // N*128
    float* a_s    = xs + (size_t)N_NODES * EMB;          // N*4
    float* a_d    = a_s + (size_t)N_NODES * 4;           // N*4
    float* csr_ae = a_d + (size_t)N_NODES * 4;           // E2*4 (16B aligned)
    float* meta   = csr_ae + (size_t)E2 * 4;             // 152
    float* gsum   = meta + 152;                          // 8*128
    float* gcnt   = gsum + NGRAPH * EMB;                 // 8
    int*   off    = (int*)(gcnt + NGRAPH);               // N+1
    int*   cursor = off + N_NODES + 1;                   // N
    int*   csr_src= cursor + N_NODES;                    // E2
    int*   csr_pos= csr_src + E2;                        // E2
    // total ~18.4M elems = 73.7 MB (< 79.3 MB proven available)

    const int EB = (E2 + 255) / 256;  // 3321

    zero_kernel<<<8, 256, 0, stream>>>(meta, 152 + NGRAPH * EMB + NGRAPH);
    zero_kernel<<<196, 256, 0, stream>>>((float*)cursor, N_NODES);  // cursor as cnt
    mean_ea_kernel<<<256, 256, 0, stream>>>(edge_attr, meta);
    prep_kernel<<<1, 128, 0, stream>>>(W_edge, att_edge, meta);
    input_proj_kernel<<<N_NODES / 16, 256, 0, stream>>>(x, W_in, b_in, h_buf);

    count_kernel<<<EB, 256, 0, stream>>>(edge_index, cursor);
    scan_kernel<<<1, 256, 0, stream>>>(cursor, off, cursor);  // reads cnt, writes off; cursor=off
    // NOTE: scan reads cursor(cnt) then overwrites it — single block, each thread
    // owns its chunk exclusively, so read-before-write is safe per-thread.
    fill_kernel<<<EB, 256, 0, stream>>>(edge_index, cursor, csr_src, csr_pos);

    for (int l = 0; l < NLAYER; l++) {
        xs_kernel<<<N_NODES / 16, 256, 0, stream>>>(
            x, h_buf, W_src + (size_t)l * GAT_IN * EMB,
            att_src + (size_t)l * EMB, att_dst + (size_t)l * EMB, xs, a_s, a_d);
        ae_fill_kernel<<<EB, 256, 0, stream>>>(edge_attr, meta, l, csr_pos, csr_ae);
        gat_gather_kernel<<<N_NODES / 4, 256, 0, stream>>>(
            off, csr_src, csr_ae, xs, a_s, a_d,
            gat_bias + (size_t)l * EMB, ln_gamma + (size_t)l * EMB,
            ln_beta + (size_t)l * EMB, h_buf);
    }

    node_head_kernel<<<N_NODES / 16, 256, 0, stream>>>(h_buf, W_out, b_out, ln_og, ln_ob, out);
    graph_head_kernel<<<N_NODES / 16, 256, 0, stream>>>(h_buf, W_g, b_g, g_gamma, g_beta,
                                                        batch, gsum, gcnt);
    graph_out_kernel<<<4, 256, 0, stream>>>(gsum, gcnt, out);
}

// Round 5
// 689.389 us; speedup vs baseline: 7.3656x; 1.3363x over previous
//
#include <hip/hip_runtime.h>

#define N_NODES 50000
#define N_EDGES 800000
#define E2      850000        // N_EDGES + N_NODES (self loops)
#define NODE_IN 32
#define EDGE_IN 16
#define EMB     128
#define GAT_IN  160           // NODE_IN + EMB
#define NLAYER  2
#define NGRAPH  8
#define NBLK    196           // ceil(N_NODES/256) for scan

// bf16 pack/unpack without hip_bf16.h (round-to-nearest-even)
__device__ __forceinline__ unsigned int f2bf(float f) {
    unsigned int u = __float_as_uint(f);
    return (u + 0x7FFFu + ((u >> 16) & 1u)) >> 16;
}
__device__ __forceinline__ float bf2f(unsigned int h) {
    return __uint_as_float(h << 16);
}
__device__ __forceinline__ unsigned int pack2bf(float a, float b) {
    return f2bf(a) | (f2bf(b) << 16);
}

// ---------------------------------------------------------------------------
__global__ void zero_kernel(float* __restrict__ p, int n) {
    int i = blockIdx.x * blockDim.x + threadIdx.x;
    int stride = gridDim.x * blockDim.x;
    for (; i < n; i += stride) p[i] = 0.f;
}

// ---------------------------------------------------------------------------
// mean of edge_attr (sums into meta[0..16)) + per-dst incoming-edge count
// ---------------------------------------------------------------------------
__global__ __launch_bounds__(256) void mean_count_kernel(const float* __restrict__ ea,
                                                         const int* __restrict__ edge_index,
                                                         float* __restrict__ meta,
                                                         int* __restrict__ cnt) {
    __shared__ float sm[EDGE_IN];
    int t = threadIdx.x;
    if (t < EDGE_IN) sm[t] = 0.f;
    __syncthreads();
    float s[EDGE_IN];
#pragma unroll
    for (int k = 0; k < EDGE_IN; k++) s[k] = 0.f;
    int gstride = gridDim.x * blockDim.x;
    for (int e = blockIdx.x * blockDim.x + t; e < N_EDGES; e += gstride) {
        const float* row = ea + (size_t)e * EDGE_IN;
#pragma unroll
        for (int k = 0; k < EDGE_IN; k++) s[k] += row[k];
    }
#pragma unroll
    for (int k = 0; k < EDGE_IN; k++) atomicAdd(&sm[k], s[k]);
    for (int e = blockIdx.x * blockDim.x + t; e < E2; e += gstride) {
        int dst = (e < N_EDGES) ? edge_index[N_EDGES + e] : (e - N_EDGES);
        atomicAdd(&cnt[dst], 1);
    }
    __syncthreads();
    if (t < EDGE_IN) atomicAdd(&meta[t], sm[t]);
}

// ---------------------------------------------------------------------------
// prep: finish mean; M[l][k][h]=sum_c W_edge[l,k,h*32+c]*att_edge[l,h,c]
// -> meta[16..144); self-loop a_e[l][h] -> meta[144..152)
// ---------------------------------------------------------------------------
__global__ void prep_kernel(const float* __restrict__ W_edge,
                            const float* __restrict__ att_edge,
                            float* __restrict__ meta) {
    int t = threadIdx.x;  // 128 threads
    if (t < EDGE_IN) meta[t] = meta[t] * (1.0f / (float)N_EDGES);
    __syncthreads();
    {
        int l = t >> 6, k = (t >> 2) & 15, h = t & 3;
        const float* w = W_edge + ((size_t)l * EDGE_IN + k) * EMB + h * 32;
        const float* a = att_edge + (size_t)l * EMB + h * 32;
        float acc = 0.f;
#pragma unroll
        for (int c = 0; c < 32; c++) acc += w[c] * a[c];
        meta[16 + (l * 16 + k) * 4 + h] = acc;
    }
    __syncthreads();
    if (t < 8) {
        int l = t >> 2, h = t & 3;
        float acc = 0.f;
#pragma unroll
        for (int k = 0; k < EDGE_IN; k++) acc += meta[k] * meta[16 + (l * 16 + k) * 4 + h];
        meta[144 + t] = acc;
    }
}

// ---------------------------------------------------------------------------
// hierarchical scan: s1 block sums -> s2 scan partials -> s3 write offsets
// ---------------------------------------------------------------------------
__global__ __launch_bounds__(256) void scan1_kernel(const int* __restrict__ cnt,
                                                    int* __restrict__ bsum) {
    __shared__ int sm[256];
    int t = threadIdx.x;
    int i = blockIdx.x * 256 + t;
    sm[t] = (i < N_NODES) ? cnt[i] : 0;
    __syncthreads();
#pragma unroll
    for (int d = 128; d >= 1; d >>= 1) {
        if (t < d) sm[t] += sm[t + d];
        __syncthreads();
    }
    if (t == 0) bsum[blockIdx.x] = sm[0];
}

__global__ __launch_bounds__(256) void scan2_kernel(const int* __restrict__ bsum,
                                                    int* __restrict__ bbase) {
    __shared__ int sm[256];
    int t = threadIdx.x;
    int v = (t < NBLK) ? bsum[t] : 0;
    sm[t] = v;
    __syncthreads();
#pragma unroll
    for (int d = 1; d < 256; d <<= 1) {
        int u = (t >= d) ? sm[t - d] : 0;
        __syncthreads();
        sm[t] += u;
        __syncthreads();
    }
    if (t < NBLK) bbase[t] = sm[t] - v;  // exclusive
}

__global__ __launch_bounds__(256) void scan3_kernel(const int* __restrict__ bbase,
                                                    int* __restrict__ cnt_cursor,  // in: cnt, out: cursor
                                                    int* __restrict__ off) {
    __shared__ int sm[256];
    int t = threadIdx.x;
    int i = blockIdx.x * 256 + t;
    int v = (i < N_NODES) ? cnt_cursor[i] : 0;
    sm[t] = v;
    __syncthreads();
#pragma unroll
    for (int d = 1; d < 256; d <<= 1) {
        int u = (t >= d) ? sm[t - d] : 0;
        __syncthreads();
        sm[t] += u;
        __syncthreads();
    }
    if (i < N_NODES) {
        int o = bbase[blockIdx.x] + sm[t] - v;  // exclusive
        off[i] = o;
        cnt_cursor[i] = o;
        if (i == N_NODES - 1) off[N_NODES] = E2;
    }
}

// ---------------------------------------------------------------------------
// fill: csr_src[pos]=src; csr_ae2[pos] = a_e for BOTH layers (8 floats)
// ---------------------------------------------------------------------------
__global__ __launch_bounds__(256) void fill_ae_kernel(const int* __restrict__ edge_index,
                                                      const float* __restrict__ edge_attr,
                                                      const float* __restrict__ meta,
                                                      int* __restrict__ cursor,
                                                      int* __restrict__ csr_src,
                                                      float* __restrict__ csr_ae2) {
    __shared__ float Ml[128];     // both layers: [l*64 + k*4 + h]
    __shared__ float loop_ae[8];  // [l*4+h]
    int t = threadIdx.x;
    if (t < 128) Ml[t] = meta[16 + t];
    if (t < 8) loop_ae[t] = meta[144 + t];
    __syncthreads();
    int e = blockIdx.x * 256 + t;
    if (e >= E2) return;
    int src, dst;
    float ae[2][4];
    if (e < N_EDGES) {
        src = edge_index[e];
        dst = edge_index[N_EDGES + e];
        const float4* r4 = (const float4*)(edge_attr + (size_t)e * EDGE_IN);
#pragma unroll
        for (int l = 0; l < 2; l++)
#pragma unroll
            for (int h = 0; h < 4; h++) ae[l][h] = 0.f;
#pragma unroll
        for (int q = 0; q < 4; q++) {
            float4 v = r4[q];
#pragma unroll
            for (int l = 0; l < 2; l++) {
                const float* M = Ml + l * 64;
#pragma unroll
                for (int h = 0; h < 4; h++) {
                    ae[l][h] += v.x * M[(4 * q + 0) * 4 + h] + v.y * M[(4 * q + 1) * 4 + h] +
                                v.z * M[(4 * q + 2) * 4 + h] + v.w * M[(4 * q + 3) * 4 + h];
                }
            }
        }
    } else {
        src = dst = e - N_EDGES;
#pragma unroll
        for (int l = 0; l < 2; l++)
#pragma unroll
            for (int h = 0; h < 4; h++) ae[l][h] = loop_ae[l * 4 + h];
    }
    int pos = atomicAdd(&cursor[dst], 1);
    csr_src[pos] = src;
    float4* o = (float4*)csr_ae2;
    o[pos * 2 + 0] = make_float4(ae[0][0], ae[0][1], ae[0][2], ae[0][3]);
    o[pos * 2 + 1] = make_float4(ae[1][0], ae[1][1], ae[1][2], ae[1][3]);
}

// ---------------------------------------------------------------------------
// h = relu(x @ W_in + b_in); 16 nodes/block, lane = 2 cols
// ---------------------------------------------------------------------------
__global__ __launch_bounds__(256) void input_proj_kernel(const float* __restrict__ x,
                                                         const float* __restrict__ W,
                                                         const float* __restrict__ b,
                                                         float* __restrict__ hbuf) {
    __shared__ float inp[16][NODE_IN];  // 2 KB
    int t = threadIdx.x;
    int n0 = blockIdx.x * 16;
    for (int i = t; i < 16 * NODE_IN; i += 256) {
        int r = i >> 5, c = i & 31;
        inp[r][c] = x[(size_t)(n0 + r) * NODE_IN + c];
    }
    __syncthreads();
    int wave = t >> 6, lane = t & 63;
    int c0 = lane * 2, c1 = c0 + 1;
    const float2* W2 = (const float2*)W;
    float acc[4][2];
#pragma unroll
    for (int j = 0; j < 4; j++) { acc[j][0] = b[c0]; acc[j][1] = b[c1]; }
#pragma unroll 8
    for (int k = 0; k < NODE_IN; k++) {
        float2 w = W2[k * 64 + lane];
#pragma unroll
        for (int j = 0; j < 4; j++) {
            float v = inp[wave * 4 + j][k];
            acc[j][0] += v * w.x;
            acc[j][1] += v * w.y;
        }
    }
    float2* out2 = (float2*)hbuf;
#pragma unroll
    for (int j = 0; j < 4; j++) {
        int n = n0 + wave * 4 + j;
        out2[(size_t)n * 64 + lane] = make_float2(fmaxf(acc[j][0], 0.f), fmaxf(acc[j][1], 0.f));
    }
}

// ---------------------------------------------------------------------------
// xs = [x|h] @ W_src[l] (stored packed bf16x2); a_s/a_d per-head dots (fp32)
// ---------------------------------------------------------------------------
__global__ __launch_bounds__(256) void xs_kernel(const float* __restrict__ x,
                                                 const float* __restrict__ hbuf,
                                                 const float* __restrict__ Wsrc_l,
                                                 const float* __restrict__ attS_l,
                                                 const float* __restrict__ attD_l,
                                                 unsigned int* __restrict__ xs,
                                                 float* __restrict__ a_s,
                                                 float* __restrict__ a_d) {
    __shared__ float inp[16][GAT_IN];  // 10.24 KB
    int t = threadIdx.x;
    int n0 = blockIdx.x * 16;
    for (int i = t; i < 16 * GAT_IN; i += 256) {
        int r = i / GAT_IN, c = i - r * GAT_IN;
        int n = n0 + r;
        inp[r][c] = (c < NODE_IN) ? x[(size_t)n * NODE_IN + c]
                                  : hbuf[(size_t)n * EMB + (c - NODE_IN)];
    }
    __syncthreads();
    int wave = t >> 6, lane = t & 63;
    int c0 = lane * 2, c1 = c0 + 1;
    const float2* W2 = (const float2*)Wsrc_l;
    float acc[4][2];
#pragma unroll
    for (int j = 0; j < 4; j++) acc[j][0] = acc[j][1] = 0.f;
#pragma unroll 8
    for (int k = 0; k < GAT_IN; k++) {
        float2 w = W2[k * 64 + lane];
#pragma unroll
        for (int j = 0; j < 4; j++) {
            float v = inp[wave * 4 + j][k];
            acc[j][0] += v * w.x;
            acc[j][1] += v * w.y;
        }
    }
    float sA = attS_l[c0], sB = attS_l[c1];
    float dA = attD_l[c0], dB = attD_l[c1];
#pragma unroll
    for (int j = 0; j < 4; j++) {
        int n = n0 + wave * 4 + j;
        xs[(size_t)n * 64 + lane] = pack2bf(acc[j][0], acc[j][1]);
        float ps = acc[j][0] * sA + acc[j][1] * sB;
        float pd = acc[j][0] * dA + acc[j][1] * dB;
#pragma unroll
        for (int off = 8; off >= 1; off >>= 1) {
            ps += __shfl_down(ps, off, 16);
            pd += __shfl_down(pd, off, 16);
        }
        if ((lane & 15) == 0) {
            int h = lane >> 4;
            a_s[(size_t)n * 4 + h] = ps;
            a_d[(size_t)n * 4 + h] = pd;
        }
    }
}

// ---------------------------------------------------------------------------
// gather: wave per node; CSR walk; softmax-weighted sum of bf16 xs[src];
// fused /denom + bias + LN + ELU. Zero atomics. 2-edge unroll for MLP.
// ---------------------------------------------------------------------------
__global__ __launch_bounds__(256) void gat_gather_kernel(const int* __restrict__ off,
                                                         const int* __restrict__ csr_src,
                                                         const float* __restrict__ csr_ae2,
                                                         int layer,
                                                         const unsigned int* __restrict__ xs,
                                                         const float* __restrict__ a_s,
                                                         const float* __restrict__ a_d,
                                                         const float* __restrict__ bias_l,
                                                         const float* __restrict__ gamma_l,
                                                         const float* __restrict__ beta_l,
                                                         float* __restrict__ hbuf) {
    int t = threadIdx.x, wave = t >> 6, lane = t & 63;
    int n = blockIdx.x * 4 + wave;  // grid = N/4 exactly
    int c0 = lane * 2, c1 = c0 + 1;
    int h = lane >> 4;
    int aoff = layer * 4 + h;
    float ad = a_d[(size_t)n * 4 + h];
    int p0 = off[n], p1 = off[n + 1];
    float den = 0.f, acc0 = 0.f, acc1 = 0.f;
    int p = p0;
    for (; p + 1 < p1; p += 2) {
        int sA = csr_src[p], sB = csr_src[p + 1];
        float aeA = csr_ae2[(size_t)p * 8 + aoff];
        float aeB = csr_ae2[(size_t)(p + 1) * 8 + aoff];
        float asA = a_s[(size_t)sA * 4 + h];
        float asB = a_s[(size_t)sB * 4 + h];
        unsigned int vA = xs[(size_t)sA * 64 + lane];
        unsigned int vB = xs[(size_t)sB * 64 + lane];
        float alA = asA + ad + aeA;
        alA = alA > 0.f ? alA : 0.2f * alA;
        float exA = __expf(alA);
        float alB = asB + ad + aeB;
        alB = alB > 0.f ? alB : 0.2f * alB;
        float exB = __expf(alB);
        den += exA + exB;
        acc0 += exA * bf2f(vA & 0xFFFFu) + exB * bf2f(vB & 0xFFFFu);
        acc1 += exA * bf2f(vA >> 16) + exB * bf2f(vB >> 16);
    }
    if (p < p1) {
        int s = csr_src[p];
        float ae = csr_ae2[(size_t)p * 8 + aoff];
        float as = a_s[(size_t)s * 4 + h];
        unsigned int v = xs[(size_t)s * 64 + lane];
        float al = as + ad + ae;
        al = al > 0.f ? al : 0.2f * al;
        float ex = __expf(al);
        den += ex;
        acc0 += ex * bf2f(v & 0xFFFFu);
        acc1 += ex * bf2f(v >> 16);
    }
    float dinv = 1.0f / (den + 1e-16f);
    float v0 = acc0 * dinv + bias_l[c0];
    float v1 = acc1 * dinv + bias_l[c1];
    float sm = v0 + v1, sq = v0 * v0 + v1 * v1;
#pragma unroll
    for (int o = 32; o >= 1; o >>= 1) {
        sm += __shfl_down(sm, o, 64);
        sq += __shfl_down(sq, o, 64);
    }
    sm = __shfl(sm, 0, 64);
    sq = __shfl(sq, 0, 64);
    float mean = sm * (1.f / EMB);
    float var = sq * (1.f / EMB) - mean * mean;
    float rstd = rsqrtf(var + 1e-5f);
    float y0 = (v0 - mean) * rstd * gamma_l[c0] + beta_l[c0];
    float y1 = (v1 - mean) * rstd * gamma_l[c1] + beta_l[c1];
    y0 = y0 > 0.f ? y0 : __expf(y0) - 1.f;  // elu
    y1 = y1 > 0.f ? y1 : __expf(y1) - 1.f;
    float2* out2 = (float2*)hbuf;
    out2[(size_t)n * 64 + lane] = make_float2(y0, y1);
}

// ---------------------------------------------------------------------------
// node head: out = LN(relu(h@W_out+b_out)); 16 nodes/block
// ---------------------------------------------------------------------------
__global__ __launch_bounds__(256) void node_head_kernel(const float* __restrict__ hbuf,
                                                        const float* __restrict__ W,
                                                        const float* __restrict__ b,
                                                        const float* __restrict__ lng,
                                                        const float* __restrict__ lnb,
                                                        float* __restrict__ out_nodes) {
    __shared__ float inp[16][EMB];  // 8 KB
    int t = threadIdx.x;
    int n0 = blockIdx.x * 16;
    for (int i = t; i < 16 * EMB; i += 256) {
        int r = i >> 7, c = i & 127;
        inp[r][c] = hbuf[(size_t)(n0 + r) * EMB + c];
    }
    __syncthreads();
    int wave = t >> 6, lane = t & 63;
    int c0 = lane * 2, c1 = c0 + 1;
    const float2* W2 = (const float2*)W;
    float acc[4][2];
#pragma unroll
    for (int j = 0; j < 4; j++) { acc[j][0] = b[c0]; acc[j][1] = b[c1]; }
#pragma unroll 8
    for (int k = 0; k < EMB; k++) {
        float2 w = W2[k * 64 + lane];
#pragma unroll
        for (int j = 0; j < 4; j++) {
            float v = inp[wave * 4 + j][k];
            acc[j][0] += v * w.x;
            acc[j][1] += v * w.y;
        }
    }
    float gA = lng[c0], gB = lng[c1], bA = lnb[c0], bB = lnb[c1];
    float2* out2 = (float2*)out_nodes;
#pragma unroll
    for (int j = 0; j < 4; j++) {
        int n = n0 + wave * 4 + j;
        float o0 = fmaxf(acc[j][0], 0.f), o1 = fmaxf(acc[j][1], 0.f);
        float sm = o0 + o1, sq = o0 * o0 + o1 * o1;
#pragma unroll
        for (int o = 32; o >= 1; o >>= 1) {
            sm += __shfl_down(sm, o, 64);
            sq += __shfl_down(sq, o, 64);
        }
        sm = __shfl(sm, 0, 64);
        sq = __shfl(sq, 0, 64);
        float m = sm * (1.f / EMB), v = sq * (1.f / EMB) - m * m;
        float r = rsqrtf(v + 1e-5f);
        out2[(size_t)n * 64 + lane] =
            make_float2((o0 - m) * r * gA + bA, (o1 - m) * r * gB + bB);
    }
}

// ---------------------------------------------------------------------------
// graph head: g = LN(relu(h@W_g+b_g)); LDS-local pooling
// ---------------------------------------------------------------------------
__global__ __launch_bounds__(256) void graph_head_kernel(const float* __restrict__ hbuf,
                                                         const float* __restrict__ W,
                                                         const float* __restrict__ b,
                                                         const float* __restrict__ gg,
                                                         const float* __restrict__ gb,
                                                         const int* __restrict__ batch,
                                                         float* __restrict__ gsum,
                                                         float* __restrict__ gcnt) {
    __shared__ float inp[16][EMB];       // 8 KB
    __shared__ float loc[NGRAPH][EMB];   // 4 KB
    __shared__ int cnts[NGRAPH];
    __shared__ int bids[16];
    int t = threadIdx.x;
    int n0 = blockIdx.x * 16;
    for (int i = t; i < 16 * EMB; i += 256) {
        int r = i >> 7, c = i & 127;
        inp[r][c] = hbuf[(size_t)(n0 + r) * EMB + c];
    }
    for (int i = t; i < NGRAPH * EMB; i += 256) ((float*)loc)[i] = 0.f;
    if (t < NGRAPH) cnts[t] = 0;
    if (t < 16) bids[t] = batch[n0 + t];
    __syncthreads();
    int wave = t >> 6, lane = t & 63;
    int c0 = lane * 2, c1 = c0 + 1;
    const float2* W2 = (const float2*)W;
    float acc[4][2];
#pragma unroll
    for (int j = 0; j < 4; j++) { acc[j][0] = b[c0]; acc[j][1] = b[c1]; }
#pragma unroll 8
    for (int k = 0; k < EMB; k++) {
        float2 w = W2[k * 64 + lane];
#pragma unroll
        for (int j = 0; j < 4; j++) {
            float v = inp[wave * 4 + j][k];
            acc[j][0] += v * w.x;
            acc[j][1] += v * w.y;
        }
    }
    float gA = gg[c0], gB = gg[c1], bA = gb[c0], bB = gb[c1];
#pragma unroll
    for (int j = 0; j < 4; j++) {
        int r = wave * 4 + j;
        float o0 = fmaxf(acc[j][0], 0.f), o1 = fmaxf(acc[j][1], 0.f);
        float sm = o0 + o1, sq = o0 * o0 + o1 * o1;
#pragma unroll
        for (int o = 32; o >= 1; o >>= 1) {
            sm += __shfl_down(sm, o, 64);
            sq += __shfl_down(sq, o, 64);
        }
        sm = __shfl(sm, 0, 64);
        sq = __shfl(sq, 0, 64);
        float m = sm * (1.f / EMB), v = sq * (1.f / EMB) - m * m;
        float rs = rsqrtf(v + 1e-5f);
        float z0 = (o0 - m) * rs * gA + bA;
        float z1 = (o1 - m) * rs * gB + bB;
        int bb = bids[r];
        atomicAdd(&loc[bb][c0], z0);
        atomicAdd(&loc[bb][c1], z1);
        if (lane == 0) atomicAdd(&cnts[bb], 1);
    }
    __syncthreads();
    int bmin = bids[0], bmax = bids[15];
    int span = (bmax - bmin + 1) * EMB;
    for (int i = t; i < span; i += 256) {
        int g = bmin + (i >> 7), c = i & 127;
        atomicAdd(&gsum[(size_t)g * EMB + c], loc[g][c]);
    }
    if (t >= bmin && t <= bmax && cnts[t] > 0) atomicAdd(&gcnt[t], (float)cnts[t]);
}

__global__ void graph_out_kernel(const float* __restrict__ gsum, const float* __restrict__ gcnt,
                                 float* __restrict__ out) {
    int i = blockIdx.x * blockDim.x + threadIdx.x;
    if (i >= NGRAPH * EMB) return;
    int b = i >> 7;
    float c = fmaxf(gcnt[b], 1.f);
    out[(size_t)N_NODES * EMB + i] = gsum[i] / c;
}

// ---------------------------------------------------------------------------
extern "C" void kernel_launch(void* const* d_in, const int* in_sizes, int n_in,
                              void* d_out, int out_size, void* d_ws, size_t ws_size,
                              hipStream_t stream) {
    (void)in_sizes; (void)n_in; (void)out_size; (void)ws_size;
    const float* x         = (const float*)d_in[0];
    const float* edge_attr = (const float*)d_in[1];
    const float* W_in      = (const float*)d_in[2];
    const float* b_in      = (const float*)d_in[3];
    const float* W_src     = (const float*)d_in[4];
    const float* W_edge    = (const float*)d_in[5];
    const float* att_src   = (const float*)d_in[6];
    const float* att_dst   = (const float*)d_in[7];
    const float* att_edge  = (const float*)d_in[8];
    const float* gat_bias  = (const float*)d_in[9];
    const float* ln_gamma  = (const float*)d_in[10];
    const float* ln_beta   = (const float*)d_in[11];
    const float* W_out     = (const float*)d_in[12];
    const float* b_out     = (const float*)d_in[13];
    const float* ln_og     = (const float*)d_in[14];
    const float* ln_ob     = (const float*)d_in[15];
    const float* W_g       = (const float*)d_in[16];
    const float* b_g       = (const float*)d_in[17];
    const float* g_gamma   = (const float*)d_in[18];
    const float* g_beta    = (const float*)d_in[19];
    const int* edge_index  = (const int*)d_in[20];
    const int* batch       = (const int*)d_in[21];
    float* out = (float*)d_out;

    float* ws       = (float*)d_ws;
    float* h_buf    = ws;                                   // N*128       6.40M
    unsigned int* xs= (unsigned int*)(h_buf + (size_t)N_NODES * EMB);  // N*64  3.20M
    float* a_s      = (float*)(xs + (size_t)N_NODES * 64);  // N*4         0.20M
    float* a_d      = a_s + (size_t)N_NODES * 4;            // N*4         0.20M
    float* csr_ae2  = a_d + (size_t)N_NODES * 4;            // E2*8        6.80M (16B aligned)
    float* meta     = csr_ae2 + (size_t)E2 * 8;             // 152
    float* gsum     = meta + 152;                           // 1024
    float* gcnt     = gsum + NGRAPH * EMB;                  // 8
    int*   off      = (int*)(gcnt + NGRAPH);                // N+1
    int*   cursor   = off + N_NODES + 1;                    // N (doubles as cnt)
    int*   csr_src  = cursor + N_NODES;                     // E2
    int*   bsum     = csr_src + E2;                         // 196
    int*   bbase    = bsum + NBLK;                          // 196
    // total ~17.8M words = 71.2 MB (< 73.7 MB proven in round 4)

    const int EB = (E2 + 255) / 256;  // 3321

    zero_kernel<<<8, 256, 0, stream>>>(meta, 152 + NGRAPH * EMB + NGRAPH);
    zero_kernel<<<NBLK, 256, 0, stream>>>((float*)cursor, N_NODES);  // cursor as cnt
    mean_count_kernel<<<256, 256, 0, stream>>>(edge_attr, edge_index, meta, cursor);
    prep_kernel<<<1, 128, 0, stream>>>(W_edge, att_edge, meta);
    input_proj_kernel<<<N_NODES / 16, 256, 0, stream>>>(x, W_in, b_in, h_buf);

    scan1_kernel<<<NBLK, 256, 0, stream>>>(cursor, bsum);
    scan2_kernel<<<1, 256, 0, stream>>>(bsum, bbase);
    scan3_kernel<<<NBLK, 256, 0, stream>>>(bbase, cursor, off);
    fill_ae_kernel<<<EB, 256, 0, stream>>>(edge_index, edge_attr, meta, cursor, csr_src, csr_ae2);

    for (int l = 0; l < NLAYER; l++) {
        xs_kernel<<<N_NODES / 16, 256, 0, stream>>>(
            x, h_buf, W_src + (size_t)l * GAT_IN * EMB,
            att_src + (size_t)l * EMB, att_dst + (size_t)l * EMB, xs, a_s, a_d);
        gat_gather_kernel<<<N_NODES / 4, 256, 0, stream>>>(
            off, csr_src, csr_ae2, l, xs, a_s, a_d,
            gat_bias + (size_t)l * EMB, ln_gamma + (size_t)l * EMB,
            ln_beta + (size_t)l * EMB, h_buf);
    }

    node_head_kernel<<<N_NODES / 16, 256, 0, stream>>>(h_buf, W_out, b_out, ln_og, ln_ob, out);
    graph_head_kernel<<<N_NODES / 16, 256, 0, stream>>>(h_buf, W_g, b_g, g_gamma, g_beta,
                                                        batch, gsum, gcnt);
    graph_out_kernel<<<4, 256, 0, stream>>>(gsum, gcnt, out);
}

// Round 6
// 601.796 us; speedup vs baseline: 8.4377x; 1.1456x over previous
//
#include <hip/hip_runtime.h>

#define N_NODES 50000
#define N_EDGES 800000
#define E2      850000        // N_EDGES + N_NODES (self loops)
#define NODE_IN 32
#define EDGE_IN 16
#define EMB     128
#define GAT_IN  160           // NODE_IN + EMB
#define NLAYER  2
#define NGRAPH  8
#define NBLK    196           // ceil(N_NODES/256) for scan
#define NB32    1563          // ceil(N_NODES/32) for GEMV kernels

// bf16 pack/unpack without hip_bf16.h (round-to-nearest-even)
__device__ __forceinline__ unsigned int f2bf(float f) {
    unsigned int u = __float_as_uint(f);
    return (u + 0x7FFFu + ((u >> 16) & 1u)) >> 16;
}
__device__ __forceinline__ float bf2f(unsigned int h) {
    return __uint_as_float(h << 16);
}
__device__ __forceinline__ unsigned int pack2bf(float a, float b) {
    return f2bf(a) | (f2bf(b) << 16);
}

// ---------------------------------------------------------------------------
__global__ void zero_kernel(float* __restrict__ p, int n) {
    int i = blockIdx.x * blockDim.x + threadIdx.x;
    int stride = gridDim.x * blockDim.x;
    for (; i < n; i += stride) p[i] = 0.f;
}

// ---------------------------------------------------------------------------
// mean of edge_attr (sums into meta[0..16)) + per-dst incoming-edge count
// ---------------------------------------------------------------------------
__global__ __launch_bounds__(256) void mean_count_kernel(const float* __restrict__ ea,
                                                         const int* __restrict__ edge_index,
                                                         float* __restrict__ meta,
                                                         int* __restrict__ cnt) {
    __shared__ float sm[EDGE_IN];
    int t = threadIdx.x;
    if (t < EDGE_IN) sm[t] = 0.f;
    __syncthreads();
    float s[EDGE_IN];
#pragma unroll
    for (int k = 0; k < EDGE_IN; k++) s[k] = 0.f;
    int gstride = gridDim.x * blockDim.x;
    for (int e = blockIdx.x * blockDim.x + t; e < N_EDGES; e += gstride) {
        const float* row = ea + (size_t)e * EDGE_IN;
#pragma unroll
        for (int k = 0; k < EDGE_IN; k++) s[k] += row[k];
    }
#pragma unroll
    for (int k = 0; k < EDGE_IN; k++) atomicAdd(&sm[k], s[k]);
    for (int e = blockIdx.x * blockDim.x + t; e < E2; e += gstride) {
        int dst = (e < N_EDGES) ? edge_index[N_EDGES + e] : (e - N_EDGES);
        atomicAdd(&cnt[dst], 1);
    }
    __syncthreads();
    if (t < EDGE_IN) atomicAdd(&meta[t], sm[t]);
}

// ---------------------------------------------------------------------------
// prep: finish mean; M[l][k][h]=sum_c W_edge[l,k,h*32+c]*att_edge[l,h,c]
// ---------------------------------------------------------------------------
__global__ void prep_kernel(const float* __restrict__ W_edge,
                            const float* __restrict__ att_edge,
                            float* __restrict__ meta) {
    int t = threadIdx.x;  // 128 threads
    if (t < EDGE_IN) meta[t] = meta[t] * (1.0f / (float)N_EDGES);
    __syncthreads();
    {
        int l = t >> 6, k = (t >> 2) & 15, h = t & 3;
        const float* w = W_edge + ((size_t)l * EDGE_IN + k) * EMB + h * 32;
        const float* a = att_edge + (size_t)l * EMB + h * 32;
        float acc = 0.f;
#pragma unroll
        for (int c = 0; c < 32; c++) acc += w[c] * a[c];
        meta[16 + (l * 16 + k) * 4 + h] = acc;
    }
    __syncthreads();
    if (t < 8) {
        int l = t >> 2, h = t & 3;
        float acc = 0.f;
#pragma unroll
        for (int k = 0; k < EDGE_IN; k++) acc += meta[k] * meta[16 + (l * 16 + k) * 4 + h];
        meta[144 + t] = acc;
    }
}

// ---------------------------------------------------------------------------
// hierarchical scan
// ---------------------------------------------------------------------------
__global__ __launch_bounds__(256) void scan1_kernel(const int* __restrict__ cnt,
                                                    int* __restrict__ bsum) {
    __shared__ int sm[256];
    int t = threadIdx.x;
    int i = blockIdx.x * 256 + t;
    sm[t] = (i < N_NODES) ? cnt[i] : 0;
    __syncthreads();
#pragma unroll
    for (int d = 128; d >= 1; d >>= 1) {
        if (t < d) sm[t] += sm[t + d];
        __syncthreads();
    }
    if (t == 0) bsum[blockIdx.x] = sm[0];
}

__global__ __launch_bounds__(256) void scan2_kernel(const int* __restrict__ bsum,
                                                    int* __restrict__ bbase) {
    __shared__ int sm[256];
    int t = threadIdx.x;
    int v = (t < NBLK) ? bsum[t] : 0;
    sm[t] = v;
    __syncthreads();
#pragma unroll
    for (int d = 1; d < 256; d <<= 1) {
        int u = (t >= d) ? sm[t - d] : 0;
        __syncthreads();
        sm[t] += u;
        __syncthreads();
    }
    if (t < NBLK) bbase[t] = sm[t] - v;  // exclusive
}

__global__ __launch_bounds__(256) void scan3_kernel(const int* __restrict__ bbase,
                                                    int* __restrict__ cnt_cursor,
                                                    int* __restrict__ off) {
    __shared__ int sm[256];
    int t = threadIdx.x;
    int i = blockIdx.x * 256 + t;
    int v = (i < N_NODES) ? cnt_cursor[i] : 0;
    sm[t] = v;
    __syncthreads();
#pragma unroll
    for (int d = 1; d < 256; d <<= 1) {
        int u = (t >= d) ? sm[t - d] : 0;
        __syncthreads();
        sm[t] += u;
        __syncthreads();
    }
    if (i < N_NODES) {
        int o = bbase[blockIdx.x] + sm[t] - v;  // exclusive
        off[i] = o;
        cnt_cursor[i] = o;
        if (i == N_NODES - 1) off[N_NODES] = E2;
    }
}

// ---------------------------------------------------------------------------
// fill: csr_src[pos]=src; csr_ae2[pos] = a_e for BOTH layers (8 floats)
// ---------------------------------------------------------------------------
__global__ __launch_bounds__(256) void fill_ae_kernel(const int* __restrict__ edge_index,
                                                      const float* __restrict__ edge_attr,
                                                      const float* __restrict__ meta,
                                                      int* __restrict__ cursor,
                                                      int* __restrict__ csr_src,
                                                      float* __restrict__ csr_ae2) {
    __shared__ float Ml[128];
    __shared__ float loop_ae[8];
    int t = threadIdx.x;
    if (t < 128) Ml[t] = meta[16 + t];
    if (t < 8) loop_ae[t] = meta[144 + t];
    __syncthreads();
    int e = blockIdx.x * 256 + t;
    if (e >= E2) return;
    int src, dst;
    float ae[2][4];
    if (e < N_EDGES) {
        src = edge_index[e];
        dst = edge_index[N_EDGES + e];
        const float4* r4 = (const float4*)(edge_attr + (size_t)e * EDGE_IN);
#pragma unroll
        for (int l = 0; l < 2; l++)
#pragma unroll
            for (int h = 0; h < 4; h++) ae[l][h] = 0.f;
#pragma unroll
        for (int q = 0; q < 4; q++) {
            float4 v = r4[q];
#pragma unroll
            for (int l = 0; l < 2; l++) {
                const float* M = Ml + l * 64;
#pragma unroll
                for (int h = 0; h < 4; h++) {
                    ae[l][h] += v.x * M[(4 * q + 0) * 4 + h] + v.y * M[(4 * q + 1) * 4 + h] +
                                v.z * M[(4 * q + 2) * 4 + h] + v.w * M[(4 * q + 3) * 4 + h];
                }
            }
        }
    } else {
        src = dst = e - N_EDGES;
#pragma unroll
        for (int l = 0; l < 2; l++)
#pragma unroll
            for (int h = 0; h < 4; h++) ae[l][h] = loop_ae[l * 4 + h];
    }
    int pos = atomicAdd(&cursor[dst], 1);
    csr_src[pos] = src;
    float4* o = (float4*)csr_ae2;
    o[pos * 2 + 0] = make_float4(ae[0][0], ae[0][1], ae[0][2], ae[0][3]);
    o[pos * 2 + 1] = make_float4(ae[1][0], ae[1][1], ae[1][2], ae[1][3]);
}

// ---------------------------------------------------------------------------
// input proj: h = relu(x @ W_in + b); 32 nodes/block (8/wave), float4 LDS reads
// ---------------------------------------------------------------------------
__global__ __launch_bounds__(256) void input_proj_kernel(const float* __restrict__ x,
                                                         const float* __restrict__ W,
                                                         const float* __restrict__ b,
                                                         float* __restrict__ hbuf) {
    __shared__ float inp[32][NODE_IN];  // 4 KB
    int t = threadIdx.x;
    int n0 = blockIdx.x * 32;
    for (int i = t; i < 32 * NODE_IN; i += 256) {
        int r = i >> 5, c = i & 31;
        int n = min(n0 + r, N_NODES - 1);
        inp[r][c] = x[(size_t)n * NODE_IN + c];
    }
    __syncthreads();
    int wave = t >> 6, lane = t & 63;
    int c0 = lane * 2, c1 = c0 + 1;
    const float2* W2 = (const float2*)W;
    float acc[8][2];
#pragma unroll
    for (int j = 0; j < 8; j++) { acc[j][0] = b[c0]; acc[j][1] = b[c1]; }
#pragma unroll 2
    for (int k4 = 0; k4 < NODE_IN / 4; k4++) {
        float4 v[8];
#pragma unroll
        for (int j = 0; j < 8; j++) v[j] = *(const float4*)&inp[wave * 8 + j][k4 * 4];
#pragma unroll
        for (int kk = 0; kk < 4; kk++) {
            float2 w = W2[(k4 * 4 + kk) * 64 + lane];
#pragma unroll
            for (int j = 0; j < 8; j++) {
                float vv = (&v[j].x)[kk];
                acc[j][0] += vv * w.x;
                acc[j][1] += vv * w.y;
            }
        }
    }
    float2* out2 = (float2*)hbuf;
#pragma unroll
    for (int j = 0; j < 8; j++) {
        int n = n0 + wave * 8 + j;
        if (n < N_NODES)
            out2[(size_t)n * 64 + lane] = make_float2(fmaxf(acc[j][0], 0.f), fmaxf(acc[j][1], 0.f));
    }
}

// ---------------------------------------------------------------------------
// xs = [x|h] @ W_src[l] (packed bf16x2) + a_s/a_d; 32 nodes/block
// ---------------------------------------------------------------------------
__global__ __launch_bounds__(256) void xs_kernel(const float* __restrict__ x,
                                                 const float* __restrict__ hbuf,
                                                 const float* __restrict__ Wsrc_l,
                                                 const float* __restrict__ attS_l,
                                                 const float* __restrict__ attD_l,
                                                 unsigned int* __restrict__ xs,
                                                 float* __restrict__ a_s,
                                                 float* __restrict__ a_d) {
    __shared__ float inp[32][GAT_IN];  // 20 KB
    int t = threadIdx.x;
    int n0 = blockIdx.x * 32;
    for (int i = t; i < 32 * GAT_IN; i += 256) {
        int r = i / GAT_IN, c = i - r * GAT_IN;
        int n = min(n0 + r, N_NODES - 1);
        inp[r][c] = (c < NODE_IN) ? x[(size_t)n * NODE_IN + c]
                                  : hbuf[(size_t)n * EMB + (c - NODE_IN)];
    }
    __syncthreads();
    int wave = t >> 6, lane = t & 63;
    int c0 = lane * 2, c1 = c0 + 1;
    const float2* W2 = (const float2*)Wsrc_l;
    float acc[8][2];
#pragma unroll
    for (int j = 0; j < 8; j++) acc[j][0] = acc[j][1] = 0.f;
#pragma unroll 2
    for (int k4 = 0; k4 < GAT_IN / 4; k4++) {
        float4 v[8];
#pragma unroll
        for (int j = 0; j < 8; j++) v[j] = *(const float4*)&inp[wave * 8 + j][k4 * 4];
#pragma unroll
        for (int kk = 0; kk < 4; kk++) {
            float2 w = W2[(k4 * 4 + kk) * 64 + lane];
#pragma unroll
            for (int j = 0; j < 8; j++) {
                float vv = (&v[j].x)[kk];
                acc[j][0] += vv * w.x;
                acc[j][1] += vv * w.y;
            }
        }
    }
    float sA = attS_l[c0], sB = attS_l[c1];
    float dA = attD_l[c0], dB = attD_l[c1];
#pragma unroll
    for (int j = 0; j < 8; j++) {
        int n = n0 + wave * 8 + j;
        float ps = acc[j][0] * sA + acc[j][1] * sB;
        float pd = acc[j][0] * dA + acc[j][1] * dB;
#pragma unroll
        for (int off = 8; off >= 1; off >>= 1) {
            ps += __shfl_down(ps, off, 16);
            pd += __shfl_down(pd, off, 16);
        }
        if (n < N_NODES) {
            xs[(size_t)n * 64 + lane] = pack2bf(acc[j][0], acc[j][1]);
            if ((lane & 15) == 0) {
                int h = lane >> 4;
                a_s[(size_t)n * 4 + h] = ps;
                a_d[(size_t)n * 4 + h] = pd;
            }
        }
    }
}

// ---------------------------------------------------------------------------
// gather: wave per node; CSR walk; softmax-weighted sum of bf16 xs[src];
// fused /denom + bias + LN + ELU. Zero atomics.
// ---------------------------------------------------------------------------
__global__ __launch_bounds__(256) void gat_gather_kernel(const int* __restrict__ off,
                                                         const int* __restrict__ csr_src,
                                                         const float* __restrict__ csr_ae2,
                                                         int layer,
                                                         const unsigned int* __restrict__ xs,
                                                         const float* __restrict__ a_s,
                                                         const float* __restrict__ a_d,
                                                         const float* __restrict__ bias_l,
                                                         const float* __restrict__ gamma_l,
                                                         const float* __restrict__ beta_l,
                                                         float* __restrict__ hbuf) {
    int t = threadIdx.x, wave = t >> 6, lane = t & 63;
    int n = blockIdx.x * 4 + wave;  // grid = N/4 exactly
    int c0 = lane * 2, c1 = c0 + 1;
    int h = lane >> 4;
    int aoff = layer * 4 + h;
    float ad = a_d[(size_t)n * 4 + h];
    int p0 = off[n], p1 = off[n + 1];
    float den = 0.f, acc0 = 0.f, acc1 = 0.f;
    int p = p0;
    for (; p + 1 < p1; p += 2) {
        int sA = csr_src[p], sB = csr_src[p + 1];
        float aeA = csr_ae2[(size_t)p * 8 + aoff];
        float aeB = csr_ae2[(size_t)(p + 1) * 8 + aoff];
        float asA = a_s[(size_t)sA * 4 + h];
        float asB = a_s[(size_t)sB * 4 + h];
        unsigned int vA = xs[(size_t)sA * 64 + lane];
        unsigned int vB = xs[(size_t)sB * 64 + lane];
        float alA = asA + ad + aeA;
        alA = alA > 0.f ? alA : 0.2f * alA;
        float exA = __expf(alA);
        float alB = asB + ad + aeB;
        alB = alB > 0.f ? alB : 0.2f * alB;
        float exB = __expf(alB);
        den += exA + exB;
        acc0 += exA * bf2f(vA & 0xFFFFu) + exB * bf2f(vB & 0xFFFFu);
        acc1 += exA * bf2f(vA >> 16) + exB * bf2f(vB >> 16);
    }
    if (p < p1) {
        int s = csr_src[p];
        float ae = csr_ae2[(size_t)p * 8 + aoff];
        float as = a_s[(size_t)s * 4 + h];
        unsigned int v = xs[(size_t)s * 64 + lane];
        float al = as + ad + ae;
        al = al > 0.f ? al : 0.2f * al;
        float ex = __expf(al);
        den += ex;
        acc0 += ex * bf2f(v & 0xFFFFu);
        acc1 += ex * bf2f(v >> 16);
    }
    float dinv = 1.0f / (den + 1e-16f);
    float v0 = acc0 * dinv + bias_l[c0];
    float v1 = acc1 * dinv + bias_l[c1];
    float sm = v0 + v1, sq = v0 * v0 + v1 * v1;
#pragma unroll
    for (int o = 32; o >= 1; o >>= 1) {
        sm += __shfl_down(sm, o, 64);
        sq += __shfl_down(sq, o, 64);
    }
    sm = __shfl(sm, 0, 64);
    sq = __shfl(sq, 0, 64);
    float mean = sm * (1.f / EMB);
    float var = sq * (1.f / EMB) - mean * mean;
    float rstd = rsqrtf(var + 1e-5f);
    float y0 = (v0 - mean) * rstd * gamma_l[c0] + beta_l[c0];
    float y1 = (v1 - mean) * rstd * gamma_l[c1] + beta_l[c1];
    y0 = y0 > 0.f ? y0 : __expf(y0) - 1.f;  // elu
    y1 = y1 > 0.f ? y1 : __expf(y1) - 1.f;
    float2* out2 = (float2*)hbuf;
    out2[(size_t)n * 64 + lane] = make_float2(y0, y1);
}

// ---------------------------------------------------------------------------
// node head: out = LN(relu(h@W_out+b)); 32 nodes/block, float4 LDS reads
// ---------------------------------------------------------------------------
__global__ __launch_bounds__(256) void node_head_kernel(const float* __restrict__ hbuf,
                                                        const float* __restrict__ W,
                                                        const float* __restrict__ b,
                                                        const float* __restrict__ lng,
                                                        const float* __restrict__ lnb,
                                                        float* __restrict__ out_nodes) {
    __shared__ float inp[32][EMB];  // 16 KB
    int t = threadIdx.x;
    int n0 = blockIdx.x * 32;
    for (int i = t; i < 32 * EMB; i += 256) {
        int r = i >> 7, c = i & 127;
        int n = min(n0 + r, N_NODES - 1);
        inp[r][c] = hbuf[(size_t)n * EMB + c];
    }
    __syncthreads();
    int wave = t >> 6, lane = t & 63;
    int c0 = lane * 2, c1 = c0 + 1;
    const float2* W2 = (const float2*)W;
    float acc[8][2];
#pragma unroll
    for (int j = 0; j < 8; j++) { acc[j][0] = b[c0]; acc[j][1] = b[c1]; }
#pragma unroll 2
    for (int k4 = 0; k4 < EMB / 4; k4++) {
        float4 v[8];
#pragma unroll
        for (int j = 0; j < 8; j++) v[j] = *(const float4*)&inp[wave * 8 + j][k4 * 4];
#pragma unroll
        for (int kk = 0; kk < 4; kk++) {
            float2 w = W2[(k4 * 4 + kk) * 64 + lane];
#pragma unroll
            for (int j = 0; j < 8; j++) {
                float vv = (&v[j].x)[kk];
                acc[j][0] += vv * w.x;
                acc[j][1] += vv * w.y;
            }
        }
    }
    float gA = lng[c0], gB = lng[c1], bA = lnb[c0], bB = lnb[c1];
    float2* out2 = (float2*)out_nodes;
#pragma unroll
    for (int j = 0; j < 8; j++) {
        int n = n0 + wave * 8 + j;
        float o0 = fmaxf(acc[j][0], 0.f), o1 = fmaxf(acc[j][1], 0.f);
        float sm = o0 + o1, sq = o0 * o0 + o1 * o1;
#pragma unroll
        for (int o = 32; o >= 1; o >>= 1) {
            sm += __shfl_down(sm, o, 64);
            sq += __shfl_down(sq, o, 64);
        }
        sm = __shfl(sm, 0, 64);
        sq = __shfl(sq, 0, 64);
        float m = sm * (1.f / EMB), v = sq * (1.f / EMB) - m * m;
        float r = rsqrtf(v + 1e-5f);
        if (n < N_NODES)
            out2[(size_t)n * 64 + lane] =
                make_float2((o0 - m) * r * gA + bA, (o1 - m) * r * gB + bB);
    }
}

// ---------------------------------------------------------------------------
// graph head: g = LN(relu(h@W_g+b)); register A/B pooling (batch sorted,
// 32-node window spans <=2 graphs; middle graphs -> direct global atomics)
// ---------------------------------------------------------------------------
__global__ __launch_bounds__(256) void graph_head_kernel(const float* __restrict__ hbuf,
                                                         const float* __restrict__ W,
                                                         const float* __restrict__ b,
                                                         const float* __restrict__ gg,
                                                         const float* __restrict__ gb,
                                                         const int* __restrict__ batch,
                                                         float* __restrict__ gsum,
                                                         float* __restrict__ gcnt) {
    __shared__ float inp[32][EMB];       // 16 KB
    __shared__ float2 red[4][2][64];     // 4 KB
    __shared__ int bids[32];
    int t = threadIdx.x;
    int n0 = blockIdx.x * 32;
    int nvalid = min(32, N_NODES - n0);
    for (int i = t; i < 32 * EMB; i += 256) {
        int r = i >> 7, c = i & 127;
        int n = min(n0 + r, N_NODES - 1);
        inp[r][c] = hbuf[(size_t)n * EMB + c];
    }
    if (t < 32) bids[t] = batch[min(n0 + t, N_NODES - 1)];
    __syncthreads();
    int bmin = bids[0], bmax = bids[nvalid - 1];
    int wave = t >> 6, lane = t & 63;
    int c0 = lane * 2, c1 = c0 + 1;
    const float2* W2 = (const float2*)W;
    float acc[8][2];
#pragma unroll
    for (int j = 0; j < 8; j++) { acc[j][0] = b[c0]; acc[j][1] = b[c1]; }
#pragma unroll 2
    for (int k4 = 0; k4 < EMB / 4; k4++) {
        float4 v[8];
#pragma unroll
        for (int j = 0; j < 8; j++) v[j] = *(const float4*)&inp[wave * 8 + j][k4 * 4];
#pragma unroll
        for (int kk = 0; kk < 4; kk++) {
            float2 w = W2[(k4 * 4 + kk) * 64 + lane];
#pragma unroll
            for (int j = 0; j < 8; j++) {
                float vv = (&v[j].x)[kk];
                acc[j][0] += vv * w.x;
                acc[j][1] += vv * w.y;
            }
        }
    }
    float gA = gg[c0], gB = gg[c1], bA = gb[c0], bB = gb[c1];
    float2 sA = make_float2(0.f, 0.f), sB = make_float2(0.f, 0.f);
#pragma unroll
    for (int j = 0; j < 8; j++) {
        int r = wave * 8 + j;
        int n = n0 + r;
        float o0 = fmaxf(acc[j][0], 0.f), o1 = fmaxf(acc[j][1], 0.f);
        float sm = o0 + o1, sq = o0 * o0 + o1 * o1;
#pragma unroll
        for (int o = 32; o >= 1; o >>= 1) {
            sm += __shfl_down(sm, o, 64);
            sq += __shfl_down(sq, o, 64);
        }
        sm = __shfl(sm, 0, 64);
        sq = __shfl(sq, 0, 64);
        float m = sm * (1.f / EMB), v = sq * (1.f / EMB) - m * m;
        float rs = rsqrtf(v + 1e-5f);
        float z0 = (o0 - m) * rs * gA + bA;
        float z1 = (o1 - m) * rs * gB + bB;
        if (n < N_NODES) {
            int bb = bids[r];
            if (bb == bmin) {
                sA.x += z0; sA.y += z1;
            } else if (bb == bmax) {
                sB.x += z0; sB.y += z1;
            } else {  // ultra-rare: graph fully inside window
                atomicAdd(&gsum[(size_t)bb * EMB + c0], z0);
                atomicAdd(&gsum[(size_t)bb * EMB + c1], z1);
            }
        }
    }
    red[wave][0][lane] = sA;
    red[wave][1][lane] = sB;
    __syncthreads();
    if (t < 64) {
        float2 a0 = red[0][0][t], a1 = red[1][0][t], a2 = red[2][0][t], a3 = red[3][0][t];
        atomicAdd(&gsum[(size_t)bmin * EMB + 2 * t],     a0.x + a1.x + a2.x + a3.x);
        atomicAdd(&gsum[(size_t)bmin * EMB + 2 * t + 1], a0.y + a1.y + a2.y + a3.y);
    } else if (t < 128 && bmax != bmin) {
        int l2 = t - 64;
        float2 a0 = red[0][1][l2], a1 = red[1][1][l2], a2 = red[2][1][l2], a3 = red[3][1][l2];
        atomicAdd(&gsum[(size_t)bmax * EMB + 2 * l2],     a0.x + a1.x + a2.x + a3.x);
        atomicAdd(&gsum[(size_t)bmax * EMB + 2 * l2 + 1], a0.y + a1.y + a2.y + a3.y);
    } else if (t == 255) {
        int cA = 0, cB = 0;
        for (int r = 0; r < nvalid; r++) {
            int bb = bids[r];
            if (bb == bmin) cA++;
            else if (bb == bmax) cB++;
            else atomicAdd(&gcnt[bb], 1.f);
        }
        atomicAdd(&gcnt[bmin], (float)cA);
        if (bmax != bmin && cB > 0) atomicAdd(&gcnt[bmax], (float)cB);
    }
}

__global__ void graph_out_kernel(const float* __restrict__ gsum, const float* __restrict__ gcnt,
                                 float* __restrict__ out) {
    int i = blockIdx.x * blockDim.x + threadIdx.x;
    if (i >= NGRAPH * EMB) return;
    int b = i >> 7;
    float c = fmaxf(gcnt[b], 1.f);
    out[(size_t)N_NODES * EMB + i] = gsum[i] / c;
}

// ---------------------------------------------------------------------------
extern "C" void kernel_launch(void* const* d_in, const int* in_sizes, int n_in,
                              void* d_out, int out_size, void* d_ws, size_t ws_size,
                              hipStream_t stream) {
    (void)in_sizes; (void)n_in; (void)out_size; (void)ws_size;
    const float* x         = (const float*)d_in[0];
    const float* edge_attr = (const float*)d_in[1];
    const float* W_in      = (const float*)d_in[2];
    const float* b_in      = (const float*)d_in[3];
    const float* W_src     = (const float*)d_in[4];
    const float* W_edge    = (const float*)d_in[5];
    const float* att_src   = (const float*)d_in[6];
    const float* att_dst   = (const float*)d_in[7];
    const float* att_edge  = (const float*)d_in[8];
    const float* gat_bias  = (const float*)d_in[9];
    const float* ln_gamma  = (const float*)d_in[10];
    const float* ln_beta   = (const float*)d_in[11];
    const float* W_out     = (const float*)d_in[12];
    const float* b_out     = (const float*)d_in[13];
    const float* ln_og     = (const float*)d_in[14];
    const float* ln_ob     = (const float*)d_in[15];
    const float* W_g       = (const float*)d_in[16];
    const float* b_g       = (const float*)d_in[17];
    const float* g_gamma   = (const float*)d_in[18];
    const float* g_beta    = (const float*)d_in[19];
    const int* edge_index  = (const int*)d_in[20];
    const int* batch       = (const int*)d_in[21];
    float* out = (float*)d_out;

    float* ws       = (float*)d_ws;
    float* h_buf    = ws;                                   // N*128
    unsigned int* xs= (unsigned int*)(h_buf + (size_t)N_NODES * EMB);  // N*64
    float* a_s      = (float*)(xs + (size_t)N_NODES * 64);  // N*4
    float* a_d      = a_s + (size_t)N_NODES * 4;            // N*4
    float* csr_ae2  = a_d + (size_t)N_NODES * 4;            // E2*8 (16B aligned)
    float* meta     = csr_ae2 + (size_t)E2 * 8;             // 152
    float* gsum     = meta + 152;                           // 1024
    float* gcnt     = gsum + NGRAPH * EMB;                  // 8
    int*   off      = (int*)(gcnt + NGRAPH);                // N+1
    int*   cursor   = off + N_NODES + 1;                    // N (doubles as cnt)
    int*   csr_src  = cursor + N_NODES;                     // E2
    int*   bsum     = csr_src + E2;                         // 196
    int*   bbase    = bsum + NBLK;                          // 196
    // total ~17.8M words = 71.2 MB

    const int EB = (E2 + 255) / 256;  // 3321

    zero_kernel<<<8, 256, 0, stream>>>(meta, 152 + NGRAPH * EMB + NGRAPH);
    zero_kernel<<<NBLK, 256, 0, stream>>>((float*)cursor, N_NODES);  // cursor as cnt
    mean_count_kernel<<<256, 256, 0, stream>>>(edge_attr, edge_index, meta, cursor);
    prep_kernel<<<1, 128, 0, stream>>>(W_edge, att_edge, meta);
    input_proj_kernel<<<NB32, 256, 0, stream>>>(x, W_in, b_in, h_buf);

    scan1_kernel<<<NBLK, 256, 0, stream>>>(cursor, bsum);
    scan2_kernel<<<1, 256, 0, stream>>>(bsum, bbase);
    scan3_kernel<<<NBLK, 256, 0, stream>>>(bbase, cursor, off);
    fill_ae_kernel<<<EB, 256, 0, stream>>>(edge_index, edge_attr, meta, cursor, csr_src, csr_ae2);

    for (int l = 0; l < NLAYER; l++) {
        xs_kernel<<<NB32, 256, 0, stream>>>(
            x, h_buf, W_src + (size_t)l * GAT_IN * EMB,
            att_src + (size_t)l * EMB, att_dst + (size_t)l * EMB, xs, a_s, a_d);
        gat_gather_kernel<<<N_NODES / 4, 256, 0, stream>>>(
            off, csr_src, csr_ae2, l, xs, a_s, a_d,
            gat_bias + (size_t)l * EMB, ln_gamma + (size_t)l * EMB,
            ln_beta + (size_t)l * EMB, h_buf);
    }

    node_head_kernel<<<NB32, 256, 0, stream>>>(h_buf, W_out, b_out, ln_og, ln_ob, out);
    graph_head_kernel<<<NB32, 256, 0, stream>>>(h_buf, W_g, b_g, g_gamma, g_beta,
                                                batch, gsum, gcnt);
    graph_out_kernel<<<4, 256, 0, stream>>>(gsum, gcnt, out);
}

// Round 7
// 554.632 us; speedup vs baseline: 9.1552x; 1.0850x over previous
//
#include <hip/hip_runtime.h>

#define N_NODES 50000
#define N_EDGES 800000
#define E2      850000        // N_EDGES + N_NODES (self loops)
#define NODE_IN 32
#define EDGE_IN 16
#define EMB     128
#define GAT_IN  160           // NODE_IN + EMB
#define NLAYER  2
#define NGRAPH  8
#define NBLK    196           // ceil(N_NODES/256) for scan
#define NB32    1563          // ceil(N_NODES/32)
#define NB64    782           // ceil(N_NODES/64) for MFMA dense kernels

typedef short bf16x8 __attribute__((ext_vector_type(8)));
typedef float f32x4 __attribute__((ext_vector_type(4)));

// bf16 pack/unpack without hip_bf16.h (round-to-nearest-even)
__device__ __forceinline__ unsigned int f2bf(float f) {
    unsigned int u = __float_as_uint(f);
    return (u + 0x7FFFu + ((u >> 16) & 1u)) >> 16;
}
__device__ __forceinline__ float bf2f(unsigned int h) {
    return __uint_as_float(h << 16);
}
__device__ __forceinline__ unsigned int pack2bf(float a, float b) {
    return f2bf(a) | (f2bf(b) << 16);
}

// ---------------------------------------------------------------------------
__global__ void zero_kernel(float* __restrict__ p, int n) {
    int i = blockIdx.x * blockDim.x + threadIdx.x;
    int stride = gridDim.x * blockDim.x;
    for (; i < n; i += stride) p[i] = 0.f;
}

// ---------------------------------------------------------------------------
// mean of edge_attr (sums into meta[0..16)) + per-dst incoming-edge count
// 1024 blocks (was 256: occupancy-starved at 9.9%)
// ---------------------------------------------------------------------------
__global__ __launch_bounds__(256) void mean_count_kernel(const float* __restrict__ ea,
                                                         const int* __restrict__ edge_index,
                                                         float* __restrict__ meta,
                                                         int* __restrict__ cnt) {
    __shared__ float sm[EDGE_IN];
    int t = threadIdx.x;
    if (t < EDGE_IN) sm[t] = 0.f;
    __syncthreads();
    float s[EDGE_IN];
#pragma unroll
    for (int k = 0; k < EDGE_IN; k++) s[k] = 0.f;
    int gstride = gridDim.x * blockDim.x;
    for (int e = blockIdx.x * blockDim.x + t; e < N_EDGES; e += gstride) {
        const float4* r4 = (const float4*)(ea + (size_t)e * EDGE_IN);
#pragma unroll
        for (int q = 0; q < 4; q++) {
            float4 v = r4[q];
            s[4 * q + 0] += v.x; s[4 * q + 1] += v.y;
            s[4 * q + 2] += v.z; s[4 * q + 3] += v.w;
        }
    }
#pragma unroll
    for (int k = 0; k < EDGE_IN; k++) atomicAdd(&sm[k], s[k]);
    for (int e = blockIdx.x * blockDim.x + t; e < E2; e += gstride) {
        int dst = (e < N_EDGES) ? edge_index[N_EDGES + e] : (e - N_EDGES);
        atomicAdd(&cnt[dst], 1);
    }
    __syncthreads();
    if (t < EDGE_IN) atomicAdd(&meta[t], sm[t]);
}

// ---------------------------------------------------------------------------
// prep: finish mean; M[l][k][h]=sum_c W_edge[l,k,h*32+c]*att_edge[l,h,c]
// ---------------------------------------------------------------------------
__global__ void prep_kernel(const float* __restrict__ W_edge,
                            const float* __restrict__ att_edge,
                            float* __restrict__ meta) {
    int t = threadIdx.x;  // 128 threads
    if (t < EDGE_IN) meta[t] = meta[t] * (1.0f / (float)N_EDGES);
    __syncthreads();
    {
        int l = t >> 6, k = (t >> 2) & 15, h = t & 3;
        const float* w = W_edge + ((size_t)l * EDGE_IN + k) * EMB + h * 32;
        const float* a = att_edge + (size_t)l * EMB + h * 32;
        float acc = 0.f;
#pragma unroll
        for (int c = 0; c < 32; c++) acc += w[c] * a[c];
        meta[16 + (l * 16 + k) * 4 + h] = acc;
    }
    __syncthreads();
    if (t < 8) {
        int l = t >> 2, h = t & 3;
        float acc = 0.f;
#pragma unroll
        for (int k = 0; k < EDGE_IN; k++) acc += meta[k] * meta[16 + (l * 16 + k) * 4 + h];
        meta[144 + t] = acc;
    }
}

// ---------------------------------------------------------------------------
// hierarchical scan
// ---------------------------------------------------------------------------
__global__ __launch_bounds__(256) void scan1_kernel(const int* __restrict__ cnt,
                                                    int* __restrict__ bsum) {
    __shared__ int sm[256];
    int t = threadIdx.x;
    int i = blockIdx.x * 256 + t;
    sm[t] = (i < N_NODES) ? cnt[i] : 0;
    __syncthreads();
#pragma unroll
    for (int d = 128; d >= 1; d >>= 1) {
        if (t < d) sm[t] += sm[t + d];
        __syncthreads();
    }
    if (t == 0) bsum[blockIdx.x] = sm[0];
}

__global__ __launch_bounds__(256) void scan2_kernel(const int* __restrict__ bsum,
                                                    int* __restrict__ bbase) {
    __shared__ int sm[256];
    int t = threadIdx.x;
    int v = (t < NBLK) ? bsum[t] : 0;
    sm[t] = v;
    __syncthreads();
#pragma unroll
    for (int d = 1; d < 256; d <<= 1) {
        int u = (t >= d) ? sm[t - d] : 0;
        __syncthreads();
        sm[t] += u;
        __syncthreads();
    }
    if (t < NBLK) bbase[t] = sm[t] - v;  // exclusive
}

__global__ __launch_bounds__(256) void scan3_kernel(const int* __restrict__ bbase,
                                                    int* __restrict__ cnt_cursor,
                                                    int* __restrict__ off) {
    __shared__ int sm[256];
    int t = threadIdx.x;
    int i = blockIdx.x * 256 + t;
    int v = (i < N_NODES) ? cnt_cursor[i] : 0;
    sm[t] = v;
    __syncthreads();
#pragma unroll
    for (int d = 1; d < 256; d <<= 1) {
        int u = (t >= d) ? sm[t - d] : 0;
        __syncthreads();
        sm[t] += u;
        __syncthreads();
    }
    if (i < N_NODES) {
        int o = bbase[blockIdx.x] + sm[t] - v;  // exclusive
        off[i] = o;
        cnt_cursor[i] = o;
        if (i == N_NODES - 1) off[N_NODES] = E2;
    }
}

// ---------------------------------------------------------------------------
// fill: csr_src[pos]=src; csr_ae2[pos] = a_e for BOTH layers (8 floats)
// ---------------------------------------------------------------------------
__global__ __launch_bounds__(256) void fill_ae_kernel(const int* __restrict__ edge_index,
                                                      const float* __restrict__ edge_attr,
                                                      const float* __restrict__ meta,
                                                      int* __restrict__ cursor,
                                                      int* __restrict__ csr_src,
                                                      float* __restrict__ csr_ae2) {
    __shared__ float Ml[128];
    __shared__ float loop_ae[8];
    int t = threadIdx.x;
    if (t < 128) Ml[t] = meta[16 + t];
    if (t < 8) loop_ae[t] = meta[144 + t];
    __syncthreads();
    int e = blockIdx.x * 256 + t;
    if (e >= E2) return;
    int src, dst;
    float ae[2][4];
    if (e < N_EDGES) {
        src = edge_index[e];
        dst = edge_index[N_EDGES + e];
        const float4* r4 = (const float4*)(edge_attr + (size_t)e * EDGE_IN);
#pragma unroll
        for (int l = 0; l < 2; l++)
#pragma unroll
            for (int h = 0; h < 4; h++) ae[l][h] = 0.f;
#pragma unroll
        for (int q = 0; q < 4; q++) {
            float4 v = r4[q];
#pragma unroll
            for (int l = 0; l < 2; l++) {
                const float* M = Ml + l * 64;
#pragma unroll
                for (int h = 0; h < 4; h++) {
                    ae[l][h] += v.x * M[(4 * q + 0) * 4 + h] + v.y * M[(4 * q + 1) * 4 + h] +
                                v.z * M[(4 * q + 2) * 4 + h] + v.w * M[(4 * q + 3) * 4 + h];
                }
            }
        }
    } else {
        src = dst = e - N_EDGES;
#pragma unroll
        for (int l = 0; l < 2; l++)
#pragma unroll
            for (int h = 0; h < 4; h++) ae[l][h] = loop_ae[l * 4 + h];
    }
    int pos = atomicAdd(&cursor[dst], 1);
    csr_src[pos] = src;
    float4* o = (float4*)csr_ae2;
    o[pos * 2 + 0] = make_float4(ae[0][0], ae[0][1], ae[0][2], ae[0][3]);
    o[pos * 2 + 1] = make_float4(ae[1][0], ae[1][1], ae[1][2], ae[1][3]);
}

// ---------------------------------------------------------------------------
// input proj: h = relu(x @ W_in + b); 32 nodes/block (8/wave) vector GEMV
// (K=32 too small for MFMA staging to pay off)
// ---------------------------------------------------------------------------
__global__ __launch_bounds__(256) void input_proj_kernel(const float* __restrict__ x,
                                                         const float* __restrict__ W,
                                                         const float* __restrict__ b,
                                                         float* __restrict__ hbuf) {
    __shared__ float inp[32][NODE_IN];  // 4 KB
    int t = threadIdx.x;
    int n0 = blockIdx.x * 32;
    for (int i = t; i < 32 * NODE_IN; i += 256) {
        int r = i >> 5, c = i & 31;
        int n = min(n0 + r, N_NODES - 1);
        inp[r][c] = x[(size_t)n * NODE_IN + c];
    }
    __syncthreads();
    int wave = t >> 6, lane = t & 63;
    int c0 = lane * 2, c1 = c0 + 1;
    const float2* W2 = (const float2*)W;
    float acc[8][2];
#pragma unroll
    for (int j = 0; j < 8; j++) { acc[j][0] = b[c0]; acc[j][1] = b[c1]; }
#pragma unroll 2
    for (int k4 = 0; k4 < NODE_IN / 4; k4++) {
        float4 v[8];
#pragma unroll
        for (int j = 0; j < 8; j++) v[j] = *(const float4*)&inp[wave * 8 + j][k4 * 4];
#pragma unroll
        for (int kk = 0; kk < 4; kk++) {
            float2 w = W2[(k4 * 4 + kk) * 64 + lane];
#pragma unroll
            for (int j = 0; j < 8; j++) {
                float vv = (&v[j].x)[kk];
                acc[j][0] += vv * w.x;
                acc[j][1] += vv * w.y;
            }
        }
    }
    float2* out2 = (float2*)hbuf;
#pragma unroll
    for (int j = 0; j < 8; j++) {
        int n = n0 + wave * 8 + j;
        if (n < N_NODES)
            out2[(size_t)n * 64 + lane] = make_float2(fmaxf(acc[j][0], 0.f), fmaxf(acc[j][1], 0.f));
    }
}

// ---------------------------------------------------------------------------
// MFMA dense kernel: C[64 nodes][128 cols] = A @ W (bf16 in, fp32 acc).
// MODE 0: xs  (A=[x|h], K=160; epilogue: pack bf16 xs + a_s/a_d head dots)
// MODE 1: node_head (A=h, K=128; epilogue: +bias, relu, LN, store fp32)
// MODE 2: graph_head (A=h, K=128; epilogue: +bias, relu, LN, masked pool)
// Wave w computes rows [16w,16w+16) x all 128 cols: 8 mfma_16x16x32 per
// 32-wide K chunk. W^T staged bf16 in LDS; A read direct from global + cvt.
// C round-trips through LDS (reusing W^T space) for row-wise epilogues.
// ---------------------------------------------------------------------------
template <int K, int MODE>
__global__ __launch_bounds__(256) void dense_mfma_kernel(
    const float* __restrict__ x, const float* __restrict__ hbuf,
    const float* __restrict__ W, const float* __restrict__ bias,
    const float* __restrict__ v1, const float* __restrict__ v2,
    const int* __restrict__ batch,
    unsigned int* __restrict__ xs_out, float* __restrict__ a_s, float* __restrict__ a_d,
    float* __restrict__ out_nodes, float* __restrict__ gsum, float* __restrict__ gcnt) {
    constexpr int KS = K + 8;                     // shorts per W^T row (16B-aligned pad)
    constexpr int WT_BYTES = 128 * KS * 2;
    constexpr int CLS = 132;                      // floats per C row (float4-aligned pad)
    constexpr int CL_BYTES = 64 * CLS * 4;
    constexpr int UNION_BYTES = (WT_BYTES > CL_BYTES ? WT_BYTES : CL_BYTES);
    __shared__ __align__(16) char smem[UNION_BYTES];
    __shared__ float red[64][8];        // LN partials [node][part + 4*{s,sq}]
    __shared__ float locw[4][2][EMB];   // MODE2 per-wave pooled partials
    __shared__ int bids[64];
    short* WT = (short*)smem;
    float* cl = (float*)smem;

    int t = threadIdx.x;
    int n0 = blockIdx.x * 64;
    // stage W^T as bf16: WT[n][k]
    for (int idx = t * 4; idx < K * 128; idx += 256 * 4) {
        float4 w4 = *(const float4*)(W + idx);
        int k = idx >> 7, n = idx & 127;
        WT[(n + 0) * KS + k] = (short)f2bf(w4.x);
        WT[(n + 1) * KS + k] = (short)f2bf(w4.y);
        WT[(n + 2) * KS + k] = (short)f2bf(w4.z);
        WT[(n + 3) * KS + k] = (short)f2bf(w4.w);
    }
    if (MODE == 2 && t < 64) bids[t] = batch[min(n0 + t, N_NODES - 1)];
    __syncthreads();

    int wave = t >> 6, lane = t & 63;
    int quad = lane >> 4, l16 = lane & 15;
    int arow = min(n0 + wave * 16 + l16, N_NODES - 1);
    f32x4 acc[8];
#pragma unroll
    for (int i = 0; i < 8; i++) acc[i] = (f32x4){0.f, 0.f, 0.f, 0.f};
#pragma unroll
    for (int kc = 0; kc < K / 32; kc++) {
        float4 av0, av1;
        if (MODE == 0 && kc == 0) {
            const float* ap = x + (size_t)arow * NODE_IN + quad * 8;
            av0 = *(const float4*)ap;
            av1 = *(const float4*)(ap + 4);
        } else {
            int hk = (MODE == 0) ? (kc - 1) * 32 : kc * 32;
            const float* ap = hbuf + (size_t)arow * EMB + hk + quad * 8;
            av0 = *(const float4*)ap;
            av1 = *(const float4*)(ap + 4);
        }
        bf16x8 af;
        af[0] = (short)f2bf(av0.x); af[1] = (short)f2bf(av0.y);
        af[2] = (short)f2bf(av0.z); af[3] = (short)f2bf(av0.w);
        af[4] = (short)f2bf(av1.x); af[5] = (short)f2bf(av1.y);
        af[6] = (short)f2bf(av1.z); af[7] = (short)f2bf(av1.w);
#pragma unroll
        for (int nt = 0; nt < 8; nt++) {
            bf16x8 bfv = *(const bf16x8*)&WT[(nt * 16 + l16) * KS + kc * 32 + quad * 8];
            acc[nt] = __builtin_amdgcn_mfma_f32_16x16x32_bf16(af, bfv, acc[nt], 0, 0, 0);
        }
    }
    __syncthreads();  // done reading WT; reuse as cl
#pragma unroll
    for (int nt = 0; nt < 8; nt++) {
#pragma unroll
        for (int i = 0; i < 4; i++) {
            int r = wave * 16 + quad * 4 + i;  // C: row = quad*4+reg, col = l16
            cl[r * CLS + nt * 16 + l16] = acc[nt][i];
        }
    }
    __syncthreads();

    // row-wise epilogue: thread t -> node r = t>>2, part p = t&3 (32 cols)
    int p = t & 3, r = t >> 2;
    int n = n0 + r;
    const float4* c4 = (const float4*)(cl + r * CLS + p * 32);

    if (MODE == 0) {
        const float4* s4 = (const float4*)(v1 + p * 32);  // att_src head p
        const float4* d4 = (const float4*)(v2 + p * 32);  // att_dst head p
        if (n < N_NODES) {
            float s_ = 0.f, d_ = 0.f;
#pragma unroll
            for (int i = 0; i < 8; i++) {
                float4 cv = c4[i], sv = s4[i], dv = d4[i];
                s_ += cv.x * sv.x + cv.y * sv.y + cv.z * sv.z + cv.w * sv.w;
                d_ += cv.x * dv.x + cv.y * dv.y + cv.z * dv.z + cv.w * dv.w;
                uint2 pk = make_uint2(pack2bf(cv.x, cv.y), pack2bf(cv.z, cv.w));
                *(uint2*)(xs_out + (size_t)n * 64 + p * 16 + 2 * i) = pk;
            }
            a_s[(size_t)n * 4 + p] = s_;
            a_d[(size_t)n * 4 + p] = d_;
        }
    } else {
        const float4* b4 = (const float4*)(bias + p * 32);
        float vals[32];
        float s_ = 0.f, q_ = 0.f;
#pragma unroll
        for (int i = 0; i < 8; i++) {
            float4 cv = c4[i], bv = b4[i];
            float w0 = fmaxf(cv.x + bv.x, 0.f), w1 = fmaxf(cv.y + bv.y, 0.f);
            float w2 = fmaxf(cv.z + bv.z, 0.f), w3 = fmaxf(cv.w + bv.w, 0.f);
            vals[4 * i] = w0; vals[4 * i + 1] = w1; vals[4 * i + 2] = w2; vals[4 * i + 3] = w3;
            s_ += w0 + w1 + w2 + w3;
            q_ += w0 * w0 + w1 * w1 + w2 * w2 + w3 * w3;
        }
        red[r][p] = s_;
        red[r][4 + p] = q_;
        __syncthreads();
        float sm = red[r][0] + red[r][1] + red[r][2] + red[r][3];
        float sq = red[r][4] + red[r][5] + red[r][6] + red[r][7];
        float mean = sm * (1.f / EMB);
        float var = sq * (1.f / EMB) - mean * mean;
        float rstd = rsqrtf(var + 1e-5f);
        const float4* g4 = (const float4*)(v1 + p * 32);
        const float4* be4 = (const float4*)(v2 + p * 32);
#pragma unroll
        for (int i = 0; i < 8; i++) {
            float4 gv = g4[i], bv = be4[i];
            vals[4 * i]     = (vals[4 * i]     - mean) * rstd * gv.x + bv.x;
            vals[4 * i + 1] = (vals[4 * i + 1] - mean) * rstd * gv.y + bv.y;
            vals[4 * i + 2] = (vals[4 * i + 2] - mean) * rstd * gv.z + bv.z;
            vals[4 * i + 3] = (vals[4 * i + 3] - mean) * rstd * gv.w + bv.w;
        }
        if (MODE == 1) {
            if (n < N_NODES) {
                float* op = out_nodes + (size_t)n * EMB + p * 32;
#pragma unroll
                for (int i = 0; i < 8; i++)
                    *(float4*)(op + 4 * i) = make_float4(vals[4 * i], vals[4 * i + 1],
                                                         vals[4 * i + 2], vals[4 * i + 3]);
            }
        } else {  // MODE 2: pooled sums (batch sorted -> <=2 graphs typical)
            int nvalid = min(64, N_NODES - n0);
            int bmin = bids[0], bmax = bids[nvalid - 1];
            int bid = bids[r];
            bool inA = (bid == bmin) && (n < N_NODES);
            bool inB = (bid == bmax) && (bmax != bmin) && (n < N_NODES);
            if (n < N_NODES && bid != bmin && bid != bmax) {  // rare middle graph
#pragma unroll
                for (int i = 0; i < 32; i++)
                    atomicAdd(&gsum[(size_t)bid * EMB + p * 32 + i], vals[i]);
            }
#pragma unroll
            for (int g = 0; g < 2; g++) {
                bool m = g ? inB : inA;
#pragma unroll
                for (int i = 0; i < 32; i++) {
                    float v = m ? vals[i] : 0.f;
                    v += __shfl_xor(v, 4, 64);
                    v += __shfl_xor(v, 8, 64);
                    v += __shfl_xor(v, 16, 64);
                    v += __shfl_xor(v, 32, 64);
                    if ((lane >> 2) == 0) locw[wave][g][(lane & 3) * 32 + i] = v;
                }
            }
            __syncthreads();
            if (t < 128) {
                float sA = locw[0][0][t] + locw[1][0][t] + locw[2][0][t] + locw[3][0][t];
                atomicAdd(&gsum[(size_t)bmin * EMB + t], sA);
                if (bmax != bmin) {
                    float sB = locw[0][1][t] + locw[1][1][t] + locw[2][1][t] + locw[3][1][t];
                    atomicAdd(&gsum[(size_t)bmax * EMB + t], sB);
                }
            } else if (t == 255) {
                int cA = 0, cB = 0;
                for (int rr = 0; rr < nvalid; rr++) {
                    int bb = bids[rr];
                    if (bb == bmin) cA++;
                    else if (bb == bmax) cB++;
                    else atomicAdd(&gcnt[bb], 1.f);
                }
                atomicAdd(&gcnt[bmin], (float)cA);
                if (bmax != bmin && cB > 0) atomicAdd(&gcnt[bmax], (float)cB);
            }
        }
    }
}

// ---------------------------------------------------------------------------
// gather: wave per node; CSR walk; softmax-weighted sum of bf16 xs[src];
// fused /denom + bias + LN + ELU. Zero atomics.
// ---------------------------------------------------------------------------
__global__ __launch_bounds__(256) void gat_gather_kernel(const int* __restrict__ off,
                                                         const int* __restrict__ csr_src,
                                                         const float* __restrict__ csr_ae2,
                                                         int layer,
                                                         const unsigned int* __restrict__ xs,
                                                         const float* __restrict__ a_s,
                                                         const float* __restrict__ a_d,
                                                         const float* __restrict__ bias_l,
                                                         const float* __restrict__ gamma_l,
                                                         const float* __restrict__ beta_l,
                                                         float* __restrict__ hbuf) {
    int t = threadIdx.x, wave = t >> 6, lane = t & 63;
    int n = blockIdx.x * 4 + wave;  // grid = N/4 exactly
    int c0 = lane * 2, c1 = c0 + 1;
    int h = lane >> 4;
    int aoff = layer * 4 + h;
    float ad = a_d[(size_t)n * 4 + h];
    int p0 = off[n], p1 = off[n + 1];
    float den = 0.f, acc0 = 0.f, acc1 = 0.f;
    int p = p0;
    for (; p + 1 < p1; p += 2) {
        int sA = csr_src[p], sB = csr_src[p + 1];
        float aeA = csr_ae2[(size_t)p * 8 + aoff];
        float aeB = csr_ae2[(size_t)(p + 1) * 8 + aoff];
        float asA = a_s[(size_t)sA * 4 + h];
        float asB = a_s[(size_t)sB * 4 + h];
        unsigned int vA = xs[(size_t)sA * 64 + lane];
        unsigned int vB = xs[(size_t)sB * 64 + lane];
        float alA = asA + ad + aeA;
        alA = alA > 0.f ? alA : 0.2f * alA;
        float exA = __expf(alA);
        float alB = asB + ad + aeB;
        alB = alB > 0.f ? alB : 0.2f * alB;
        float exB = __expf(alB);
        den += exA + exB;
        acc0 += exA * bf2f(vA & 0xFFFFu) + exB * bf2f(vB & 0xFFFFu);
        acc1 += exA * bf2f(vA >> 16) + exB * bf2f(vB >> 16);
    }
    if (p < p1) {
        int s = csr_src[p];
        float ae = csr_ae2[(size_t)p * 8 + aoff];
        float as = a_s[(size_t)s * 4 + h];
        unsigned int v = xs[(size_t)s * 64 + lane];
        float al = as + ad + ae;
        al = al > 0.f ? al : 0.2f * al;
        float ex = __expf(al);
        den += ex;
        acc0 += ex * bf2f(v & 0xFFFFu);
        acc1 += ex * bf2f(v >> 16);
    }
    float dinv = 1.0f / (den + 1e-16f);
    float v0 = acc0 * dinv + bias_l[c0];
    float v1 = acc1 * dinv + bias_l[c1];
    float sm = v0 + v1, sq = v0 * v0 + v1 * v1;
#pragma unroll
    for (int o = 32; o >= 1; o >>= 1) {
        sm += __shfl_down(sm, o, 64);
        sq += __shfl_down(sq, o, 64);
    }
    sm = __shfl(sm, 0, 64);
    sq = __shfl(sq, 0, 64);
    float mean = sm * (1.f / EMB);
    float var = sq * (1.f / EMB) - mean * mean;
    float rstd = rsqrtf(var + 1e-5f);
    float y0 = (v0 - mean) * rstd * gamma_l[c0] + beta_l[c0];
    float y1 = (v1 - mean) * rstd * gamma_l[c1] + beta_l[c1];
    y0 = y0 > 0.f ? y0 : __expf(y0) - 1.f;  // elu
    y1 = y1 > 0.f ? y1 : __expf(y1) - 1.f;
    float2* out2 = (float2*)hbuf;
    out2[(size_t)n * 64 + lane] = make_float2(y0, y1);
}

__global__ void graph_out_kernel(const float* __restrict__ gsum, const float* __restrict__ gcnt,
                                 float* __restrict__ out) {
    int i = blockIdx.x * blockDim.x + threadIdx.x;
    if (i >= NGRAPH * EMB) return;
    int b = i >> 7;
    float c = fmaxf(gcnt[b], 1.f);
    out[(size_t)N_NODES * EMB + i] = gsum[i] / c;
}

// ---------------------------------------------------------------------------
extern "C" void kernel_launch(void* const* d_in, const int* in_sizes, int n_in,
                              void* d_out, int out_size, void* d_ws, size_t ws_size,
                              hipStream_t stream) {
    (void)in_sizes; (void)n_in; (void)out_size; (void)ws_size;
    const float* x         = (const float*)d_in[0];
    const float* edge_attr = (const float*)d_in[1];
    const float* W_in      = (const float*)d_in[2];
    const float* b_in      = (const float*)d_in[3];
    const float* W_src     = (const float*)d_in[4];
    const float* W_edge    = (const float*)d_in[5];
    const float* att_src   = (const float*)d_in[6];
    const float* att_dst   = (const float*)d_in[7];
    const float* att_edge  = (const float*)d_in[8];
    const float* gat_bias  = (const float*)d_in[9];
    const float* ln_gamma  = (const float*)d_in[10];
    const float* ln_beta   = (const float*)d_in[11];
    const float* W_out     = (const float*)d_in[12];
    const float* b_out     = (const float*)d_in[13];
    const float* ln_og     = (const float*)d_in[14];
    const float* ln_ob     = (const float*)d_in[15];
    const float* W_g       = (const float*)d_in[16];
    const float* b_g       = (const float*)d_in[17];
    const float* g_gamma   = (const float*)d_in[18];
    const float* g_beta    = (const float*)d_in[19];
    const int* edge_index  = (const int*)d_in[20];
    const int* batch       = (const int*)d_in[21];
    float* out = (float*)d_out;

    float* ws       = (float*)d_ws;
    float* h_buf    = ws;                                   // N*128
    unsigned int* xs= (unsigned int*)(h_buf + (size_t)N_NODES * EMB);  // N*64
    float* a_s      = (float*)(xs + (size_t)N_NODES * 64);  // N*4
    float* a_d      = a_s + (size_t)N_NODES * 4;            // N*4
    float* csr_ae2  = a_d + (size_t)N_NODES * 4;            // E2*8 (16B aligned)
    float* meta     = csr_ae2 + (size_t)E2 * 8;             // 152
    float* gsum     = meta + 152;                           // 1024
    float* gcnt     = gsum + NGRAPH * EMB;                  // 8
    int*   off      = (int*)(gcnt + NGRAPH);                // N+1
    int*   cursor   = off + N_NODES + 1;                    // N (doubles as cnt)
    int*   csr_src  = cursor + N_NODES;                     // E2
    int*   bsum     = csr_src + E2;                         // 196
    int*   bbase    = bsum + NBLK;                          // 196
    // total ~17.8M words = 71.2 MB

    const int EB = (E2 + 255) / 256;  // 3321

    zero_kernel<<<8, 256, 0, stream>>>(meta, 152 + NGRAPH * EMB + NGRAPH);
    zero_kernel<<<NBLK, 256, 0, stream>>>((float*)cursor, N_NODES);  // cursor as cnt
    mean_count_kernel<<<1024, 256, 0, stream>>>(edge_attr, edge_index, meta, cursor);
    prep_kernel<<<1, 128, 0, stream>>>(W_edge, att_edge, meta);
    input_proj_kernel<<<NB32, 256, 0, stream>>>(x, W_in, b_in, h_buf);

    scan1_kernel<<<NBLK, 256, 0, stream>>>(cursor, bsum);
    scan2_kernel<<<1, 256, 0, stream>>>(bsum, bbase);
    scan3_kernel<<<NBLK, 256, 0, stream>>>(bbase, cursor, off);
    fill_ae_kernel<<<EB, 256, 0, stream>>>(edge_index, edge_attr, meta, cursor, csr_src, csr_ae2);

    for (int l = 0; l < NLAYER; l++) {
        dense_mfma_kernel<GAT_IN, 0><<<NB64, 256, 0, stream>>>(
            x, h_buf, W_src + (size_t)l * GAT_IN * EMB, nullptr,
            att_src + (size_t)l * EMB, att_dst + (size_t)l * EMB, nullptr,
            xs, a_s, a_d, nullptr, nullptr, nullptr);
        gat_gather_kernel<<<N_NODES / 4, 256, 0, stream>>>(
            off, csr_src, csr_ae2, l, xs, a_s, a_d,
            gat_bias + (size_t)l * EMB, ln_gamma + (size_t)l * EMB,
            ln_beta + (size_t)l * EMB, h_buf);
    }

    dense_mfma_kernel<EMB, 1><<<NB64, 256, 0, stream>>>(
        nullptr, h_buf, W_out, b_out, ln_og, ln_ob, nullptr,
        nullptr, nullptr, nullptr, out, nullptr, nullptr);
    dense_mfma_kernel<EMB, 2><<<NB64, 256, 0, stream>>>(
        nullptr, h_buf, W_g, b_g, g_gamma, g_beta, batch,
        nullptr, nullptr, nullptr, nullptr, gsum, gcnt);
    graph_out_kernel<<<4, 256, 0, stream>>>(gsum, gcnt, out);
}

// Round 8
// 519.500 us; speedup vs baseline: 9.7743x; 1.0676x over previous
//
#include <hip/hip_runtime.h>

#define N_NODES 50000
#define N_EDGES 800000
#define E2      850000        // N_EDGES + N_NODES (self loops)
#define NODE_IN 32
#define EDGE_IN 16
#define EMB     128
#define GAT_IN  160           // NODE_IN + EMB
#define NLAYER  2
#define NGRAPH  8
#define NBLK    196           // ceil(N_NODES/256) for scan
#define NB32    1563          // ceil(N_NODES/32)
#define NB64    782           // ceil(N_NODES/64) for MFMA dense kernels

typedef short bf16x8 __attribute__((ext_vector_type(8)));
typedef float f32x4 __attribute__((ext_vector_type(4)));

// bf16 pack/unpack without hip_bf16.h (round-to-nearest-even)
__device__ __forceinline__ unsigned int f2bf(float f) {
    unsigned int u = __float_as_uint(f);
    return (u + 0x7FFFu + ((u >> 16) & 1u)) >> 16;
}
__device__ __forceinline__ float bf2f(unsigned int h) {
    return __uint_as_float(h << 16);
}
__device__ __forceinline__ unsigned int pack2bf(float a, float b) {
    return f2bf(a) | (f2bf(b) << 16);
}

// ---------------------------------------------------------------------------
__global__ void zero_kernel(float* __restrict__ p, int n) {
    int i = blockIdx.x * blockDim.x + threadIdx.x;
    int stride = gridDim.x * blockDim.x;
    for (; i < n; i += stride) p[i] = 0.f;
}

// ---------------------------------------------------------------------------
// mean of edge_attr: flat float4 stream, 2048 blocks. Sums into meta[0..16).
// thread's float4-class q = gid&3 is invariant (stride % 4 == 0).
// ---------------------------------------------------------------------------
__global__ __launch_bounds__(256) void mean_kernel(const float* __restrict__ ea,
                                                   float* __restrict__ meta) {
    __shared__ float sm[16];
    int t = threadIdx.x;
    if (t < 16) sm[t] = 0.f;
    __syncthreads();
    int gid = blockIdx.x * 256 + t;
    int q = gid & 3;
    const float4* ea4 = (const float4*)ea;
    float4 s = make_float4(0.f, 0.f, 0.f, 0.f);
    for (int j = gid; j < N_EDGES * 4; j += 2048 * 256) {
        float4 v = ea4[j];
        s.x += v.x; s.y += v.y; s.z += v.z; s.w += v.w;
    }
    atomicAdd(&sm[q * 4 + 0], s.x);
    atomicAdd(&sm[q * 4 + 1], s.y);
    atomicAdd(&sm[q * 4 + 2], s.z);
    atomicAdd(&sm[q * 4 + 3], s.w);
    __syncthreads();
    if (t < 16) atomicAdd(&meta[t], sm[t]);
}

// ---------------------------------------------------------------------------
// prep: finish mean; M[l][k][h]=sum_c W_edge[l,k,h*32+c]*att_edge[l,h,c]
// ---------------------------------------------------------------------------
__global__ void prep_kernel(const float* __restrict__ W_edge,
                            const float* __restrict__ att_edge,
                            float* __restrict__ meta) {
    int t = threadIdx.x;  // 128 threads
    if (t < EDGE_IN) meta[t] = meta[t] * (1.0f / (float)N_EDGES);
    __syncthreads();
    {
        int l = t >> 6, k = (t >> 2) & 15, h = t & 3;
        const float* w = W_edge + ((size_t)l * EDGE_IN + k) * EMB + h * 32;
        const float* a = att_edge + (size_t)l * EMB + h * 32;
        float acc = 0.f;
#pragma unroll
        for (int c = 0; c < 32; c++) acc += w[c] * a[c];
        meta[16 + (l * 16 + k) * 4 + h] = acc;
    }
    __syncthreads();
    if (t < 8) {
        int l = t >> 2, h = t & 3;
        float acc = 0.f;
#pragma unroll
        for (int k = 0; k < EDGE_IN; k++) acc += meta[k] * meta[16 + (l * 16 + k) * 4 + h];
        meta[144 + t] = acc;
    }
}

// ---------------------------------------------------------------------------
// count+rank: sharded histogram (shard = blockIdx&3, shard-major layout ->
// different cache lines, contention /4). rank[e] = old count = position of
// edge e within its (shard,dst) group. Block b covers exactly [256b,256b+256).
// ---------------------------------------------------------------------------
__global__ __launch_bounds__(256) void count_rank_kernel(const int* __restrict__ edge_index,
                                                         int* __restrict__ cnt4,
                                                         int* __restrict__ rank) {
    int e = blockIdx.x * 256 + threadIdx.x;
    if (e >= E2) return;
    int dst = (e < N_EDGES) ? edge_index[N_EDGES + e] : (e - N_EDGES);
    int shard = blockIdx.x & 3;
    rank[e] = atomicAdd(&cnt4[shard * N_NODES + dst], 1);
}

// ---------------------------------------------------------------------------
// hierarchical scan over total counts; scan3 also emits per-shard bases
// ---------------------------------------------------------------------------
__global__ __launch_bounds__(256) void scan1_kernel(const int* __restrict__ cnt4,
                                                    int* __restrict__ bsum) {
    __shared__ int sm[256];
    int t = threadIdx.x;
    int i = blockIdx.x * 256 + t;
    int tot = 0;
    if (i < N_NODES) {
#pragma unroll
        for (int s = 0; s < 4; s++) tot += cnt4[s * N_NODES + i];
    }
    sm[t] = tot;
    __syncthreads();
#pragma unroll
    for (int d = 128; d >= 1; d >>= 1) {
        if (t < d) sm[t] += sm[t + d];
        __syncthreads();
    }
    if (t == 0) bsum[blockIdx.x] = sm[0];
}

__global__ __launch_bounds__(256) void scan2_kernel(const int* __restrict__ bsum,
                                                    int* __restrict__ bbase) {
    __shared__ int sm[256];
    int t = threadIdx.x;
    int v = (t < NBLK) ? bsum[t] : 0;
    sm[t] = v;
    __syncthreads();
#pragma unroll
    for (int d = 1; d < 256; d <<= 1) {
        int u = (t >= d) ? sm[t - d] : 0;
        __syncthreads();
        sm[t] += u;
        __syncthreads();
    }
    if (t < NBLK) bbase[t] = sm[t] - v;  // exclusive
}

__global__ __launch_bounds__(256) void scan3_kernel(const int* __restrict__ bbase,
                                                    const int* __restrict__ cnt4,
                                                    int* __restrict__ off,
                                                    int* __restrict__ shard_base) {
    __shared__ int sm[256];
    int t = threadIdx.x;
    int i = blockIdx.x * 256 + t;
    int c[4] = {0, 0, 0, 0};
    int tot = 0;
    if (i < N_NODES) {
#pragma unroll
        for (int s = 0; s < 4; s++) {
            c[s] = cnt4[s * N_NODES + i];
            tot += c[s];
        }
    }
    sm[t] = tot;
    __syncthreads();
#pragma unroll
    for (int d = 1; d < 256; d <<= 1) {
        int u = (t >= d) ? sm[t - d] : 0;
        __syncthreads();
        sm[t] += u;
        __syncthreads();
    }
    if (i < N_NODES) {
        int base = bbase[blockIdx.x] + sm[t] - tot;  // exclusive
        off[i] = base;
        int4 sb;
        sb.x = base;            base += c[0];
        sb.y = base;            base += c[1];
        sb.z = base;            base += c[2];
        sb.w = base;
        *(int4*)(shard_base + i * 4) = sb;
        if (i == N_NODES - 1) off[N_NODES] = E2;
    }
}

// ---------------------------------------------------------------------------
// fill (ATOMIC-FREE): pos = shard_base[dst][shard(e)] + rank[e].
// csr_src[pos]=src; ae SoA per layer: csr_ae_l[pos*4+h].
// ---------------------------------------------------------------------------
__global__ __launch_bounds__(256) void fill_ae_kernel(const int* __restrict__ edge_index,
                                                      const float* __restrict__ edge_attr,
                                                      const float* __restrict__ meta,
                                                      const int* __restrict__ rank,
                                                      const int* __restrict__ shard_base,
                                                      int* __restrict__ csr_src,
                                                      float* __restrict__ csr_ae0,
                                                      float* __restrict__ csr_ae1) {
    __shared__ float Ml[128];
    __shared__ float loop_ae[8];
    int t = threadIdx.x;
    if (t < 128) Ml[t] = meta[16 + t];
    if (t < 8) loop_ae[t] = meta[144 + t];
    __syncthreads();
    int e = blockIdx.x * 256 + t;
    if (e >= E2) return;
    int src, dst;
    float ae[2][4];
    if (e < N_EDGES) {
        src = edge_index[e];
        dst = edge_index[N_EDGES + e];
        const float4* r4 = (const float4*)(edge_attr + (size_t)e * EDGE_IN);
#pragma unroll
        for (int l = 0; l < 2; l++)
#pragma unroll
            for (int h = 0; h < 4; h++) ae[l][h] = 0.f;
#pragma unroll
        for (int q = 0; q < 4; q++) {
            float4 v = r4[q];
#pragma unroll
            for (int l = 0; l < 2; l++) {
                const float* M = Ml + l * 64;
#pragma unroll
                for (int h = 0; h < 4; h++) {
                    ae[l][h] += v.x * M[(4 * q + 0) * 4 + h] + v.y * M[(4 * q + 1) * 4 + h] +
                                v.z * M[(4 * q + 2) * 4 + h] + v.w * M[(4 * q + 3) * 4 + h];
                }
            }
        }
    } else {
        src = dst = e - N_EDGES;
#pragma unroll
        for (int l = 0; l < 2; l++)
#pragma unroll
            for (int h = 0; h < 4; h++) ae[l][h] = loop_ae[l * 4 + h];
    }
    int shard = (e >> 8) & 3;  // matches count_rank's blockIdx&3
    int pos = shard_base[dst * 4 + shard] + rank[e];
    csr_src[pos] = src;
    *(float4*)(csr_ae0 + (size_t)pos * 4) = make_float4(ae[0][0], ae[0][1], ae[0][2], ae[0][3]);
    *(float4*)(csr_ae1 + (size_t)pos * 4) = make_float4(ae[1][0], ae[1][1], ae[1][2], ae[1][3]);
}

// ---------------------------------------------------------------------------
// input proj: h = relu(x @ W_in + b); 32 nodes/block (8/wave) vector GEMV
// ---------------------------------------------------------------------------
__global__ __launch_bounds__(256) void input_proj_kernel(const float* __restrict__ x,
                                                         const float* __restrict__ W,
                                                         const float* __restrict__ b,
                                                         float* __restrict__ hbuf) {
    __shared__ float inp[32][NODE_IN];  // 4 KB
    int t = threadIdx.x;
    int n0 = blockIdx.x * 32;
    for (int i = t; i < 32 * NODE_IN; i += 256) {
        int r = i >> 5, c = i & 31;
        int n = min(n0 + r, N_NODES - 1);
        inp[r][c] = x[(size_t)n * NODE_IN + c];
    }
    __syncthreads();
    int wave = t >> 6, lane = t & 63;
    int c0 = lane * 2, c1 = c0 + 1;
    const float2* W2 = (const float2*)W;
    float acc[8][2];
#pragma unroll
    for (int j = 0; j < 8; j++) { acc[j][0] = b[c0]; acc[j][1] = b[c1]; }
#pragma unroll 2
    for (int k4 = 0; k4 < NODE_IN / 4; k4++) {
        float4 v[8];
#pragma unroll
        for (int j = 0; j < 8; j++) v[j] = *(const float4*)&inp[wave * 8 + j][k4 * 4];
#pragma unroll
        for (int kk = 0; kk < 4; kk++) {
            float2 w = W2[(k4 * 4 + kk) * 64 + lane];
#pragma unroll
            for (int j = 0; j < 8; j++) {
                float vv = (&v[j].x)[kk];
                acc[j][0] += vv * w.x;
                acc[j][1] += vv * w.y;
            }
        }
    }
    float2* out2 = (float2*)hbuf;
#pragma unroll
    for (int j = 0; j < 8; j++) {
        int n = n0 + wave * 8 + j;
        if (n < N_NODES)
            out2[(size_t)n * 64 + lane] = make_float2(fmaxf(acc[j][0], 0.f), fmaxf(acc[j][1], 0.f));
    }
}

// ---------------------------------------------------------------------------
// MFMA dense kernel (as round 7): C[64][128] = A @ W, bf16 in fp32 acc.
// ---------------------------------------------------------------------------
template <int K, int MODE>
__global__ __launch_bounds__(256) void dense_mfma_kernel(
    const float* __restrict__ x, const float* __restrict__ hbuf,
    const float* __restrict__ W, const float* __restrict__ bias,
    const float* __restrict__ v1, const float* __restrict__ v2,
    const int* __restrict__ batch,
    unsigned int* __restrict__ xs_out, float* __restrict__ a_s, float* __restrict__ a_d,
    float* __restrict__ out_nodes, float* __restrict__ gsum, float* __restrict__ gcnt) {
    constexpr int KS = K + 8;
    constexpr int WT_BYTES = 128 * KS * 2;
    constexpr int CLS = 132;
    constexpr int CL_BYTES = 64 * CLS * 4;
    constexpr int UNION_BYTES = (WT_BYTES > CL_BYTES ? WT_BYTES : CL_BYTES);
    __shared__ __align__(16) char smem[UNION_BYTES];
    __shared__ float red[64][8];
    __shared__ float locw[4][2][EMB];
    __shared__ int bids[64];
    short* WT = (short*)smem;
    float* cl = (float*)smem;

    int t = threadIdx.x;
    int n0 = blockIdx.x * 64;
    for (int idx = t * 4; idx < K * 128; idx += 256 * 4) {
        float4 w4 = *(const float4*)(W + idx);
        int k = idx >> 7, n = idx & 127;
        WT[(n + 0) * KS + k] = (short)f2bf(w4.x);
        WT[(n + 1) * KS + k] = (short)f2bf(w4.y);
        WT[(n + 2) * KS + k] = (short)f2bf(w4.z);
        WT[(n + 3) * KS + k] = (short)f2bf(w4.w);
    }
    if (MODE == 2 && t < 64) bids[t] = batch[min(n0 + t, N_NODES - 1)];
    __syncthreads();

    int wave = t >> 6, lane = t & 63;
    int quad = lane >> 4, l16 = lane & 15;
    int arow = min(n0 + wave * 16 + l16, N_NODES - 1);
    f32x4 acc[8];
#pragma unroll
    for (int i = 0; i < 8; i++) acc[i] = (f32x4){0.f, 0.f, 0.f, 0.f};
#pragma unroll
    for (int kc = 0; kc < K / 32; kc++) {
        float4 av0, av1;
        if (MODE == 0 && kc == 0) {
            const float* ap = x + (size_t)arow * NODE_IN + quad * 8;
            av0 = *(const float4*)ap;
            av1 = *(const float4*)(ap + 4);
        } else {
            int hk = (MODE == 0) ? (kc - 1) * 32 : kc * 32;
            const float* ap = hbuf + (size_t)arow * EMB + hk + quad * 8;
            av0 = *(const float4*)ap;
            av1 = *(const float4*)(ap + 4);
        }
        bf16x8 af;
        af[0] = (short)f2bf(av0.x); af[1] = (short)f2bf(av0.y);
        af[2] = (short)f2bf(av0.z); af[3] = (short)f2bf(av0.w);
        af[4] = (short)f2bf(av1.x); af[5] = (short)f2bf(av1.y);
        af[6] = (short)f2bf(av1.z); af[7] = (short)f2bf(av1.w);
#pragma unroll
        for (int nt = 0; nt < 8; nt++) {
            bf16x8 bfv = *(const bf16x8*)&WT[(nt * 16 + l16) * KS + kc * 32 + quad * 8];
            acc[nt] = __builtin_amdgcn_mfma_f32_16x16x32_bf16(af, bfv, acc[nt], 0, 0, 0);
        }
    }
    __syncthreads();
#pragma unroll
    for (int nt = 0; nt < 8; nt++) {
#pragma unroll
        for (int i = 0; i < 4; i++) {
            int r = wave * 16 + quad * 4 + i;
            cl[r * CLS + nt * 16 + l16] = acc[nt][i];
        }
    }
    __syncthreads();

    int p = t & 3, r = t >> 2;
    int n = n0 + r;
    const float4* c4 = (const float4*)(cl + r * CLS + p * 32);

    if (MODE == 0) {
        const float4* s4 = (const float4*)(v1 + p * 32);
        const float4* d4 = (const float4*)(v2 + p * 32);
        if (n < N_NODES) {
            float s_ = 0.f, d_ = 0.f;
#pragma unroll
            for (int i = 0; i < 8; i++) {
                float4 cv = c4[i], sv = s4[i], dv = d4[i];
                s_ += cv.x * sv.x + cv.y * sv.y + cv.z * sv.z + cv.w * sv.w;
                d_ += cv.x * dv.x + cv.y * dv.y + cv.z * dv.z + cv.w * dv.w;
                uint2 pk = make_uint2(pack2bf(cv.x, cv.y), pack2bf(cv.z, cv.w));
                *(uint2*)(xs_out + (size_t)n * 64 + p * 16 + 2 * i) = pk;
            }
            a_s[(size_t)n * 4 + p] = s_;
            a_d[(size_t)n * 4 + p] = d_;
        }
    } else {
        const float4* b4 = (const float4*)(bias + p * 32);
        float vals[32];
        float s_ = 0.f, q_ = 0.f;
#pragma unroll
        for (int i = 0; i < 8; i++) {
            float4 cv = c4[i], bv = b4[i];
            float w0 = fmaxf(cv.x + bv.x, 0.f), w1 = fmaxf(cv.y + bv.y, 0.f);
            float w2 = fmaxf(cv.z + bv.z, 0.f), w3 = fmaxf(cv.w + bv.w, 0.f);
            vals[4 * i] = w0; vals[4 * i + 1] = w1; vals[4 * i + 2] = w2; vals[4 * i + 3] = w3;
            s_ += w0 + w1 + w2 + w3;
            q_ += w0 * w0 + w1 * w1 + w2 * w2 + w3 * w3;
        }
        red[r][p] = s_;
        red[r][4 + p] = q_;
        __syncthreads();
        float sm = red[r][0] + red[r][1] + red[r][2] + red[r][3];
        float sq = red[r][4] + red[r][5] + red[r][6] + red[r][7];
        float mean = sm * (1.f / EMB);
        float var = sq * (1.f / EMB) - mean * mean;
        float rstd = rsqrtf(var + 1e-5f);
        const float4* g4 = (const float4*)(v1 + p * 32);
        const float4* be4 = (const float4*)(v2 + p * 32);
#pragma unroll
        for (int i = 0; i < 8; i++) {
            float4 gv = g4[i], bv = be4[i];
            vals[4 * i]     = (vals[4 * i]     - mean) * rstd * gv.x + bv.x;
            vals[4 * i + 1] = (vals[4 * i + 1] - mean) * rstd * gv.y + bv.y;
            vals[4 * i + 2] = (vals[4 * i + 2] - mean) * rstd * gv.z + bv.z;
            vals[4 * i + 3] = (vals[4 * i + 3] - mean) * rstd * gv.w + bv.w;
        }
        if (MODE == 1) {
            if (n < N_NODES) {
                float* op = out_nodes + (size_t)n * EMB + p * 32;
#pragma unroll
                for (int i = 0; i < 8; i++)
                    *(float4*)(op + 4 * i) = make_float4(vals[4 * i], vals[4 * i + 1],
                                                         vals[4 * i + 2], vals[4 * i + 3]);
            }
        } else {
            int nvalid = min(64, N_NODES - n0);
            int bmin = bids[0], bmax = bids[nvalid - 1];
            int bid = bids[r];
            bool inA = (bid == bmin) && (n < N_NODES);
            bool inB = (bid == bmax) && (bmax != bmin) && (n < N_NODES);
            if (n < N_NODES && bid != bmin && bid != bmax) {
#pragma unroll
                for (int i = 0; i < 32; i++)
                    atomicAdd(&gsum[(size_t)bid * EMB + p * 32 + i], vals[i]);
            }
#pragma unroll
            for (int g = 0; g < 2; g++) {
                bool m = g ? inB : inA;
#pragma unroll
                for (int i = 0; i < 32; i++) {
                    float v = m ? vals[i] : 0.f;
                    v += __shfl_xor(v, 4, 64);
                    v += __shfl_xor(v, 8, 64);
                    v += __shfl_xor(v, 16, 64);
                    v += __shfl_xor(v, 32, 64);
                    if ((lane >> 2) == 0) locw[wave][g][(lane & 3) * 32 + i] = v;
                }
            }
            __syncthreads();
            if (t < 128) {
                float sA = locw[0][0][t] + locw[1][0][t] + locw[2][0][t] + locw[3][0][t];
                atomicAdd(&gsum[(size_t)bmin * EMB + t], sA);
                if (bmax != bmin) {
                    float sB = locw[0][1][t] + locw[1][1][t] + locw[2][1][t] + locw[3][1][t];
                    atomicAdd(&gsum[(size_t)bmax * EMB + t], sB);
                }
            } else if (t == 255) {
                int cA = 0, cB = 0;
                for (int rr = 0; rr < nvalid; rr++) {
                    int bb = bids[rr];
                    if (bb == bmin) cA++;
                    else if (bb == bmax) cB++;
                    else atomicAdd(&gcnt[bb], 1.f);
                }
                atomicAdd(&gcnt[bmin], (float)cA);
                if (bmax != bmin && cB > 0) atomicAdd(&gcnt[bmax], (float)cB);
            }
        }
    }
}

// ---------------------------------------------------------------------------
// gather: wave per node; CSR walk; softmax-weighted sum of bf16 xs[src];
// fused /denom + bias + LN + ELU. Zero atomics. SoA ae (16B/edge/layer).
// ---------------------------------------------------------------------------
__global__ __launch_bounds__(256) void gat_gather_kernel(const int* __restrict__ off,
                                                         const int* __restrict__ csr_src,
                                                         const float* __restrict__ csr_ae,
                                                         const unsigned int* __restrict__ xs,
                                                         const float* __restrict__ a_s,
                                                         const float* __restrict__ a_d,
                                                         const float* __restrict__ bias_l,
                                                         const float* __restrict__ gamma_l,
                                                         const float* __restrict__ beta_l,
                                                         float* __restrict__ hbuf) {
    int t = threadIdx.x, wave = t >> 6, lane = t & 63;
    int n = blockIdx.x * 4 + wave;  // grid = N/4 exactly
    int c0 = lane * 2, c1 = c0 + 1;
    int h = lane >> 4;
    float ad = a_d[(size_t)n * 4 + h];
    int p0 = __builtin_amdgcn_readfirstlane(off[n]);
    int p1 = __builtin_amdgcn_readfirstlane(off[n + 1]);
    float den = 0.f, acc0 = 0.f, acc1 = 0.f;
    int p = p0;
    for (; p + 1 < p1; p += 2) {
        int sA = csr_src[p], sB = csr_src[p + 1];
        float aeA = csr_ae[(size_t)p * 4 + h];
        float aeB = csr_ae[(size_t)(p + 1) * 4 + h];
        float asA = a_s[(size_t)sA * 4 + h];
        float asB = a_s[(size_t)sB * 4 + h];
        unsigned int vA = xs[(size_t)sA * 64 + lane];
        unsigned int vB = xs[(size_t)sB * 64 + lane];
        float alA = asA + ad + aeA;
        alA = alA > 0.f ? alA : 0.2f * alA;
        float exA = __expf(alA);
        float alB = asB + ad + aeB;
        alB = alB > 0.f ? alB : 0.2f * alB;
        float exB = __expf(alB);
        den += exA + exB;
        acc0 += exA * bf2f(vA & 0xFFFFu) + exB * bf2f(vB & 0xFFFFu);
        acc1 += exA * bf2f(vA >> 16) + exB * bf2f(vB >> 16);
    }
    if (p < p1) {
        int s = csr_src[p];
        float ae = csr_ae[(size_t)p * 4 + h];
        float as = a_s[(size_t)s * 4 + h];
        unsigned int v = xs[(size_t)s * 64 + lane];
        float al = as + ad + ae;
        al = al > 0.f ? al : 0.2f * al;
        float ex = __expf(al);
        den += ex;
        acc0 += ex * bf2f(v & 0xFFFFu);
        acc1 += ex * bf2f(v >> 16);
    }
    float dinv = 1.0f / (den + 1e-16f);
    float v0 = acc0 * dinv + bias_l[c0];
    float v1 = acc1 * dinv + bias_l[c1];
    float sm = v0 + v1, sq = v0 * v0 + v1 * v1;
#pragma unroll
    for (int o = 32; o >= 1; o >>= 1) {
        sm += __shfl_down(sm, o, 64);
        sq += __shfl_down(sq, o, 64);
    }
    sm = __shfl(sm, 0, 64);
    sq = __shfl(sq, 0, 64);
    float mean = sm * (1.f / EMB);
    float var = sq * (1.f / EMB) - mean * mean;
    float rstd = rsqrtf(var + 1e-5f);
    float y0 = (v0 - mean) * rstd * gamma_l[c0] + beta_l[c0];
    float y1 = (v1 - mean) * rstd * gamma_l[c1] + beta_l[c1];
    y0 = y0 > 0.f ? y0 : __expf(y0) - 1.f;  // elu
    y1 = y1 > 0.f ? y1 : __expf(y1) - 1.f;
    float2* out2 = (float2*)hbuf;
    out2[(size_t)n * 64 + lane] = make_float2(y0, y1);
}

__global__ void graph_out_kernel(const float* __restrict__ gsum, const float* __restrict__ gcnt,
                                 float* __restrict__ out) {
    int i = blockIdx.x * blockDim.x + threadIdx.x;
    if (i >= NGRAPH * EMB) return;
    int b = i >> 7;
    float c = fmaxf(gcnt[b], 1.f);
    out[(size_t)N_NODES * EMB + i] = gsum[i] / c;
}

// ---------------------------------------------------------------------------
extern "C" void kernel_launch(void* const* d_in, const int* in_sizes, int n_in,
                              void* d_out, int out_size, void* d_ws, size_t ws_size,
                              hipStream_t stream) {
    (void)in_sizes; (void)n_in; (void)out_size; (void)ws_size;
    const float* x         = (const float*)d_in[0];
    const float* edge_attr = (const float*)d_in[1];
    const float* W_in      = (const float*)d_in[2];
    const float* b_in      = (const float*)d_in[3];
    const float* W_src     = (const float*)d_in[4];
    const float* W_edge    = (const float*)d_in[5];
    const float* att_src   = (const float*)d_in[6];
    const float* att_dst   = (const float*)d_in[7];
    const float* att_edge  = (const float*)d_in[8];
    const float* gat_bias  = (const float*)d_in[9];
    const float* ln_gamma  = (const float*)d_in[10];
    const float* ln_beta   = (const float*)d_in[11];
    const float* W_out     = (const float*)d_in[12];
    const float* b_out     = (const float*)d_in[13];
    const float* ln_og     = (const float*)d_in[14];
    const float* ln_ob     = (const float*)d_in[15];
    const float* W_g       = (const float*)d_in[16];
    const float* b_g       = (const float*)d_in[17];
    const float* g_gamma   = (const float*)d_in[18];
    const float* g_beta    = (const float*)d_in[19];
    const int* edge_index  = (const int*)d_in[20];
    const int* batch       = (const int*)d_in[21];
    float* out = (float*)d_out;

    float* ws        = (float*)d_ws;
    float* h_buf     = ws;                                    // N*128
    unsigned int* xs = (unsigned int*)(h_buf + (size_t)N_NODES * EMB);  // N*64
    float* a_s       = (float*)(xs + (size_t)N_NODES * 64);   // N*4
    float* a_d       = a_s + (size_t)N_NODES * 4;             // N*4
    float* csr_ae    = a_d + (size_t)N_NODES * 4;             // 2 * E2*4 (16B aligned)
    float* meta      = csr_ae + (size_t)2 * E2 * 4;           // 152
    float* gsum      = meta + 152;                            // 1024
    float* gcnt      = gsum + NGRAPH * EMB;                   // 8
    int*   cnt4      = (int*)(gcnt + NGRAPH);                 // 4*N (shard-major)
    int*   off       = cnt4 + 4 * N_NODES;                    // N+1
    int*   shard_base= off + N_NODES + 1;                     // 4*N (node-major)
    int*   rank      = shard_base + 4 * N_NODES;              // E2
    int*   csr_src   = rank + E2;                             // E2
    int*   bsum      = csr_src + E2;                          // NBLK
    int*   bbase     = bsum + NBLK;                           // NBLK
    // total ~19.0M words = 75.8 MB (< 79.3 MB proven in round 3)

    const int EB = (E2 + 255) / 256;  // 3321

    // one zero pass: meta(152)+gsum(1024)+gcnt(8)+cnt4(200000) contiguous
    zero_kernel<<<256, 256, 0, stream>>>(meta, 152 + NGRAPH * EMB + NGRAPH + 4 * N_NODES);
    mean_kernel<<<2048, 256, 0, stream>>>(edge_attr, meta);
    prep_kernel<<<1, 128, 0, stream>>>(W_edge, att_edge, meta);
    input_proj_kernel<<<NB32, 256, 0, stream>>>(x, W_in, b_in, h_buf);

    count_rank_kernel<<<EB, 256, 0, stream>>>(edge_index, cnt4, rank);
    scan1_kernel<<<NBLK, 256, 0, stream>>>(cnt4, bsum);
    scan2_kernel<<<1, 256, 0, stream>>>(bsum, bbase);
    scan3_kernel<<<NBLK, 256, 0, stream>>>(bbase, cnt4, off, shard_base);
    fill_ae_kernel<<<EB, 256, 0, stream>>>(edge_index, edge_attr, meta, rank, shard_base,
                                           csr_src, csr_ae, csr_ae + (size_t)E2 * 4);

    for (int l = 0; l < NLAYER; l++) {
        dense_mfma_kernel<GAT_IN, 0><<<NB64, 256, 0, stream>>>(
            x, h_buf, W_src + (size_t)l * GAT_IN * EMB, nullptr,
            att_src + (size_t)l * EMB, att_dst + (size_t)l * EMB, nullptr,
            xs, a_s, a_d, nullptr, nullptr, nullptr);
        gat_gather_kernel<<<N_NODES / 4, 256, 0, stream>>>(
            off, csr_src, csr_ae + (size_t)l * E2 * 4, xs, a_s, a_d,
            gat_bias + (size_t)l * EMB, ln_gamma + (size_t)l * EMB,
            ln_beta + (size_t)l * EMB, h_buf);
    }

    dense_mfma_kernel<EMB, 1><<<NB64, 256, 0, stream>>>(
        nullptr, h_buf, W_out, b_out, ln_og, ln_ob, nullptr,
        nullptr, nullptr, nullptr, out, nullptr, nullptr);
    dense_mfma_kernel<EMB, 2><<<NB64, 256, 0, stream>>>(
        nullptr, h_buf, W_g, b_g, g_gamma, g_beta, batch,
        nullptr, nullptr, nullptr, nullptr, gsum, gcnt);
    graph_out_kernel<<<4, 256, 0, stream>>>(gsum, gcnt, out);
}

// Round 10
// 476.376 us; speedup vs baseline: 10.6592x; 1.0905x over previous
//
#include <hip/hip_runtime.h>

#define N_NODES 50000
#define N_EDGES 800000
#define E2      850000        // N_EDGES + N_NODES (self loops)
#define NODE_IN 32
#define EDGE_IN 16
#define EMB     128
#define GAT_IN  160           // NODE_IN + EMB
#define NLAYER  2
#define NGRAPH  8
#define NBLK    196           // ceil(N_NODES/256) for scan
#define NB32    1563          // ceil(N_NODES/32)
#define NB64    782           // ceil(N_NODES/64) for MFMA dense kernels

// gwt (fragment-ordered bf16 W^T) offsets in shorts
#define GWT_SRC0 0
#define GWT_SRC1 20480
#define GWT_OUT  40960
#define GWT_G    57344
#define GWT_TOT  73728

typedef short bf16x8 __attribute__((ext_vector_type(8)));
typedef float f32x4 __attribute__((ext_vector_type(4)));

// bf16 pack/unpack without hip_bf16.h (round-to-nearest-even)
__device__ __forceinline__ unsigned int f2bf(float f) {
    unsigned int u = __float_as_uint(f);
    return (u + 0x7FFFu + ((u >> 16) & 1u)) >> 16;
}
__device__ __forceinline__ float bf2f(unsigned int h) {
    return __uint_as_float(h << 16);
}
__device__ __forceinline__ unsigned int pack2bf(float a, float b) {
    return f2bf(a) | (f2bf(b) << 16);
}

// ---------------------------------------------------------------------------
__global__ void zero_kernel(float* __restrict__ p, int n) {
    int i = blockIdx.x * blockDim.x + threadIdx.x;
    int stride = gridDim.x * blockDim.x;
    for (; i < n; i += stride) p[i] = 0.f;
}

// ---------------------------------------------------------------------------
// mean of edge_attr: flat float4 stream. Sums into meta[0..16).
// ---------------------------------------------------------------------------
__global__ __launch_bounds__(256) void mean_kernel(const float* __restrict__ ea,
                                                   float* __restrict__ meta) {
    __shared__ float sm[16];
    int t = threadIdx.x;
    if (t < 16) sm[t] = 0.f;
    __syncthreads();
    int gid = blockIdx.x * 256 + t;
    int q = gid & 3;
    const float4* ea4 = (const float4*)ea;
    float4 s = make_float4(0.f, 0.f, 0.f, 0.f);
    for (int j = gid; j < N_EDGES * 4; j += 2048 * 256) {
        float4 v = ea4[j];
        s.x += v.x; s.y += v.y; s.z += v.z; s.w += v.w;
    }
    atomicAdd(&sm[q * 4 + 0], s.x);
    atomicAdd(&sm[q * 4 + 1], s.y);
    atomicAdd(&sm[q * 4 + 2], s.z);
    atomicAdd(&sm[q * 4 + 3], s.w);
    __syncthreads();
    if (t < 16) atomicAdd(&meta[t], sm[t]);
}

// ---------------------------------------------------------------------------
// prep: finish mean; M[l][k][h]=sum_c W_edge[l,k,h*32+c]*att_edge[l,h,c]
// ---------------------------------------------------------------------------
__global__ void prep_kernel(const float* __restrict__ W_edge,
                            const float* __restrict__ att_edge,
                            float* __restrict__ meta) {
    int t = threadIdx.x;  // 128 threads
    if (t < EDGE_IN) meta[t] = meta[t] * (1.0f / (float)N_EDGES);
    __syncthreads();
    {
        int l = t >> 6, k = (t >> 2) & 15, h = t & 3;
        const float* w = W_edge + ((size_t)l * EDGE_IN + k) * EMB + h * 32;
        const float* a = att_edge + (size_t)l * EMB + h * 32;
        float acc = 0.f;
#pragma unroll
        for (int c = 0; c < 32; c++) acc += w[c] * a[c];
        meta[16 + (l * 16 + k) * 4 + h] = acc;
    }
    __syncthreads();
    if (t < 8) {
        int l = t >> 2, h = t & 3;
        float acc = 0.f;
#pragma unroll
        for (int k = 0; k < EDGE_IN; k++) acc += meta[k] * meta[16 + (l * 16 + k) * 4 + h];
        meta[144 + t] = acc;
    }
}

// ---------------------------------------------------------------------------
// prep_wt: pre-transpose W_src[0,1], W_out, W_g into bf16 fragment order:
// gwt[base + ((kc*8+nt)*64 + lane)*8 + j] = bf16(W[kc*32+quad*8+j][nt*16+l16])
// -> a wave's MFMA B-fragment is one coalesced 16B/lane global load.
// grid = 36 x 256 = 9216 groups exactly.
// ---------------------------------------------------------------------------
__global__ __launch_bounds__(256) void prep_wt_kernel(const float* __restrict__ Wsrc,
                                                      const float* __restrict__ Wout,
                                                      const float* __restrict__ Wg,
                                                      unsigned short* __restrict__ gwt) {
    int g = blockIdx.x * 256 + threadIdx.x;
    const float* Wm;
    int base, gg;
    if (g < 5120) {        // W_src layer 0/1, K=160: 2560 groups each
        int l = g / 2560;
        gg = g - l * 2560;
        Wm = Wsrc + (size_t)l * GAT_IN * EMB;
        base = l * 20480;
    } else if (g < 7168) { // W_out, K=128: 2048 groups
        gg = g - 5120;
        Wm = Wout;
        base = GWT_OUT;
    } else {               // W_g
        gg = g - 7168;
        Wm = Wg;
        base = GWT_G;
    }
    int lane = gg & 63, tmp = gg >> 6;
    int nt = tmp & 7, kc = tmp >> 3;
    int quad = lane >> 4, l16 = lane & 15;
    int col = nt * 16 + l16, k0 = kc * 32 + quad * 8;
    unsigned int u[4];
#pragma unroll
    for (int j = 0; j < 4; j++)
        u[j] = pack2bf(Wm[(size_t)(k0 + 2 * j) * EMB + col], Wm[(size_t)(k0 + 2 * j + 1) * EMB + col]);
    *(uint4*)(gwt + base + (size_t)gg * 8) = make_uint4(u[0], u[1], u[2], u[3]);
}

// ---------------------------------------------------------------------------
// count+rank: sharded histogram; rank[e] = within-(shard,dst) position
// ---------------------------------------------------------------------------
__global__ __launch_bounds__(256) void count_rank_kernel(const int* __restrict__ edge_index,
                                                         int* __restrict__ cnt4,
                                                         int* __restrict__ rank) {
    int e = blockIdx.x * 256 + threadIdx.x;
    if (e >= E2) return;
    int dst = (e < N_EDGES) ? edge_index[N_EDGES + e] : (e - N_EDGES);
    int shard = blockIdx.x & 3;
    rank[e] = atomicAdd(&cnt4[shard * N_NODES + dst], 1);
}

// ---------------------------------------------------------------------------
// hierarchical scan; scan3 emits per-shard bases
// ---------------------------------------------------------------------------
__global__ __launch_bounds__(256) void scan1_kernel(const int* __restrict__ cnt4,
                                                    int* __restrict__ bsum) {
    __shared__ int sm[256];
    int t = threadIdx.x;
    int i = blockIdx.x * 256 + t;
    int tot = 0;
    if (i < N_NODES) {
#pragma unroll
        for (int s = 0; s < 4; s++) tot += cnt4[s * N_NODES + i];
    }
    sm[t] = tot;
    __syncthreads();
#pragma unroll
    for (int d = 128; d >= 1; d >>= 1) {
        if (t < d) sm[t] += sm[t + d];
        __syncthreads();
    }
    if (t == 0) bsum[blockIdx.x] = sm[0];
}

__global__ __launch_bounds__(256) void scan2_kernel(const int* __restrict__ bsum,
                                                    int* __restrict__ bbase) {
    __shared__ int sm[256];
    int t = threadIdx.x;
    int v = (t < NBLK) ? bsum[t] : 0;
    sm[t] = v;
    __syncthreads();
#pragma unroll
    for (int d = 1; d < 256; d <<= 1) {
        int u = (t >= d) ? sm[t - d] : 0;
        __syncthreads();
        sm[t] += u;
        __syncthreads();
    }
    if (t < NBLK) bbase[t] = sm[t] - v;  // exclusive
}

__global__ __launch_bounds__(256) void scan3_kernel(const int* __restrict__ bbase,
                                                    const int* __restrict__ cnt4,
                                                    int* __restrict__ off,
                                                    int* __restrict__ shard_base) {
    __shared__ int sm[256];
    int t = threadIdx.x;
    int i = blockIdx.x * 256 + t;
    int c[4] = {0, 0, 0, 0};
    int tot = 0;
    if (i < N_NODES) {
#pragma unroll
        for (int s = 0; s < 4; s++) {
            c[s] = cnt4[s * N_NODES + i];
            tot += c[s];
        }
    }
    sm[t] = tot;
    __syncthreads();
#pragma unroll
    for (int d = 1; d < 256; d <<= 1) {
        int u = (t >= d) ? sm[t - d] : 0;
        __syncthreads();
        sm[t] += u;
        __syncthreads();
    }
    if (i < N_NODES) {
        int base = bbase[blockIdx.x] + sm[t] - tot;  // exclusive
        off[i] = base;
        int4 sb;
        sb.x = base;            base += c[0];
        sb.y = base;            base += c[1];
        sb.z = base;            base += c[2];
        sb.w = base;
        *(int4*)(shard_base + i * 4) = sb;
        if (i == N_NODES - 1) off[N_NODES] = E2;
    }
}

// ---------------------------------------------------------------------------
// fill (atomic-free): pos = shard_base[dst][shard(e)] + rank[e]
// ---------------------------------------------------------------------------
__global__ __launch_bounds__(256) void fill_ae_kernel(const int* __restrict__ edge_index,
                                                      const float* __restrict__ edge_attr,
                                                      const float* __restrict__ meta,
                                                      const int* __restrict__ rank,
                                                      const int* __restrict__ shard_base,
                                                      int* __restrict__ csr_src,
                                                      float* __restrict__ csr_ae0,
                                                      float* __restrict__ csr_ae1) {
    __shared__ float Ml[128];
    __shared__ float loop_ae[8];
    int t = threadIdx.x;
    if (t < 128) Ml[t] = meta[16 + t];
    if (t < 8) loop_ae[t] = meta[144 + t];
    __syncthreads();
    int e = blockIdx.x * 256 + t;
    if (e >= E2) return;
    int src, dst;
    float ae[2][4];
    if (e < N_EDGES) {
        src = edge_index[e];
        dst = edge_index[N_EDGES + e];
        const float4* r4 = (const float4*)(edge_attr + (size_t)e * EDGE_IN);
#pragma unroll
        for (int l = 0; l < 2; l++)
#pragma unroll
            for (int h = 0; h < 4; h++) ae[l][h] = 0.f;
#pragma unroll
        for (int q = 0; q < 4; q++) {
            float4 v = r4[q];
#pragma unroll
            for (int l = 0; l < 2; l++) {
                const float* M = Ml + l * 64;
#pragma unroll
                for (int h = 0; h < 4; h++) {
                    ae[l][h] += v.x * M[(4 * q + 0) * 4 + h] + v.y * M[(4 * q + 1) * 4 + h] +
                                v.z * M[(4 * q + 2) * 4 + h] + v.w * M[(4 * q + 3) * 4 + h];
                }
            }
        }
    } else {
        src = dst = e - N_EDGES;
#pragma unroll
        for (int l = 0; l < 2; l++)
#pragma unroll
            for (int h = 0; h < 4; h++) ae[l][h] = loop_ae[l * 4 + h];
    }
    int shard = (e >> 8) & 3;  // matches count_rank's blockIdx&3
    int pos = shard_base[dst * 4 + shard] + rank[e];
    csr_src[pos] = src;
    *(float4*)(csr_ae0 + (size_t)pos * 4) = make_float4(ae[0][0], ae[0][1], ae[0][2], ae[0][3]);
    *(float4*)(csr_ae1 + (size_t)pos * 4) = make_float4(ae[1][0], ae[1][1], ae[1][2], ae[1][3]);
}

// ---------------------------------------------------------------------------
// input proj: h = relu(x @ W_in + b) -> h_bf (packed bf16); also emits x_bf
// ---------------------------------------------------------------------------
__global__ __launch_bounds__(256) void input_proj_kernel(const float* __restrict__ x,
                                                         const float* __restrict__ W,
                                                         const float* __restrict__ b,
                                                         unsigned int* __restrict__ h_bf,
                                                         unsigned int* __restrict__ x_bf) {
    __shared__ float inp[32][NODE_IN];  // 4 KB
    int t = threadIdx.x;
    int n0 = blockIdx.x * 32;
    for (int i = t; i < 32 * NODE_IN; i += 256) {
        int r = i >> 5, c = i & 31;
        int n = min(n0 + r, N_NODES - 1);
        inp[r][c] = x[(size_t)n * NODE_IN + c];
    }
    __syncthreads();
    // x_bf: 32 nodes x 16 packed pairs
    for (int i = t; i < 32 * 16; i += 256) {
        int r = i >> 4, c = i & 15;
        int n = n0 + r;
        if (n < N_NODES) x_bf[(size_t)n * 16 + c] = pack2bf(inp[r][2 * c], inp[r][2 * c + 1]);
    }
    int wave = t >> 6, lane = t & 63;
    int c0 = lane * 2, c1 = c0 + 1;
    const float2* W2 = (const float2*)W;
    float acc[8][2];
#pragma unroll
    for (int j = 0; j < 8; j++) { acc[j][0] = b[c0]; acc[j][1] = b[c1]; }
#pragma unroll 2
    for (int k4 = 0; k4 < NODE_IN / 4; k4++) {
        float4 v[8];
#pragma unroll
        for (int j = 0; j < 8; j++) v[j] = *(const float4*)&inp[wave * 8 + j][k4 * 4];
#pragma unroll
        for (int kk = 0; kk < 4; kk++) {
            float2 w = W2[(k4 * 4 + kk) * 64 + lane];
#pragma unroll
            for (int j = 0; j < 8; j++) {
                float vv = (&v[j].x)[kk];
                acc[j][0] += vv * w.x;
                acc[j][1] += vv * w.y;
            }
        }
    }
#pragma unroll
    for (int j = 0; j < 8; j++) {
        int n = n0 + wave * 8 + j;
        if (n < N_NODES)
            h_bf[(size_t)n * 64 + lane] = pack2bf(fmaxf(acc[j][0], 0.f), fmaxf(acc[j][1], 0.f));
    }
}

// ---------------------------------------------------------------------------
// MFMA dense kernel: C[64 nodes][128] = A @ W. A from bf16-packed global
// (x_bf/h_bf), B from pre-transposed fragment-ordered gwt (global, L2-hot).
// NO W staging, NO transpose, one barrier before epilogue.
// A-chunk offset is in UINTS: 16 uints = 32 bf16 per K-chunk (r9 bug: was 8).
// ---------------------------------------------------------------------------
template <int K, int MODE>
__global__ __launch_bounds__(256) void dense_mfma_kernel(
    const unsigned int* __restrict__ xbf, const unsigned int* __restrict__ hbf,
    const unsigned short* __restrict__ gwt, const float* __restrict__ bias,
    const float* __restrict__ v1, const float* __restrict__ v2,
    const int* __restrict__ batch,
    unsigned int* __restrict__ xs_out, float* __restrict__ a_s, float* __restrict__ a_d,
    float* __restrict__ out_nodes, float* __restrict__ gsum, float* __restrict__ gcnt) {
    constexpr int CLS = 132;
    __shared__ __align__(16) float cl[64 * CLS];            // 33 KB
    __shared__ float red[(MODE != 0) ? 64 : 1][8];
    __shared__ float locw[(MODE == 2) ? 4 : 1][2][EMB];
    __shared__ int bids[(MODE == 2) ? 64 : 1];

    int t = threadIdx.x;
    int n0 = blockIdx.x * 64;
    if (MODE == 2 && t < 64) bids[t] = batch[min(n0 + t, N_NODES - 1)];

    int wave = t >> 6, lane = t & 63;
    int quad = lane >> 4, l16 = lane & 15;
    int arow = min(n0 + wave * 16 + l16, N_NODES - 1);
    const bf16x8* B = (const bf16x8*)gwt;
    f32x4 acc[8];
#pragma unroll
    for (int i = 0; i < 8; i++) acc[i] = (f32x4){0.f, 0.f, 0.f, 0.f};
#pragma unroll
    for (int kc = 0; kc < K / 32; kc++) {
        bf16x8 af;
        if (MODE == 0 && kc == 0) {
            af = *(const bf16x8*)(xbf + (size_t)arow * 16 + quad * 4);
        } else {
            int hk = ((MODE == 0) ? (kc - 1) : kc) * 16;  // UINT units (32 bf16/chunk)
            af = *(const bf16x8*)(hbf + (size_t)arow * 64 + hk + quad * 4);
        }
#pragma unroll
        for (int nt = 0; nt < 8; nt++) {
            bf16x8 bfv = B[(kc * 8 + nt) * 64 + lane];
            acc[nt] = __builtin_amdgcn_mfma_f32_16x16x32_bf16(af, bfv, acc[nt], 0, 0, 0);
        }
    }
#pragma unroll
    for (int nt = 0; nt < 8; nt++) {
#pragma unroll
        for (int i = 0; i < 4; i++) {
            int r = wave * 16 + quad * 4 + i;  // C: row = quad*4+reg, col = l16
            cl[r * CLS + nt * 16 + l16] = acc[nt][i];
        }
    }
    __syncthreads();

    // row-wise epilogue: thread t -> node r = t>>2, part p = t&3 (32 cols)
    int p = t & 3, r = t >> 2;
    int n = n0 + r;
    const float4* c4 = (const float4*)(cl + r * CLS + p * 32);

    if (MODE == 0) {
        const float4* s4 = (const float4*)(v1 + p * 32);
        const float4* d4 = (const float4*)(v2 + p * 32);
        if (n < N_NODES) {
            float s_ = 0.f, d_ = 0.f;
#pragma unroll
            for (int i = 0; i < 8; i++) {
                float4 cv = c4[i], sv = s4[i], dv = d4[i];
                s_ += cv.x * sv.x + cv.y * sv.y + cv.z * sv.z + cv.w * sv.w;
                d_ += cv.x * dv.x + cv.y * dv.y + cv.z * dv.z + cv.w * dv.w;
                uint2 pk = make_uint2(pack2bf(cv.x, cv.y), pack2bf(cv.z, cv.w));
                *(uint2*)(xs_out + (size_t)n * 64 + p * 16 + 2 * i) = pk;
            }
            a_s[(size_t)n * 4 + p] = s_;
            a_d[(size_t)n * 4 + p] = d_;
        }
    } else {
        const float4* b4 = (const float4*)(bias + p * 32);
        float vals[32];
        float s_ = 0.f, q_ = 0.f;
#pragma unroll
        for (int i = 0; i < 8; i++) {
            float4 cv = c4[i], bv = b4[i];
            float w0 = fmaxf(cv.x + bv.x, 0.f), w1 = fmaxf(cv.y + bv.y, 0.f);
            float w2 = fmaxf(cv.z + bv.z, 0.f), w3 = fmaxf(cv.w + bv.w, 0.f);
            vals[4 * i] = w0; vals[4 * i + 1] = w1; vals[4 * i + 2] = w2; vals[4 * i + 3] = w3;
            s_ += w0 + w1 + w2 + w3;
            q_ += w0 * w0 + w1 * w1 + w2 * w2 + w3 * w3;
        }
        red[r][p] = s_;
        red[r][4 + p] = q_;
        __syncthreads();
        float sm = red[r][0] + red[r][1] + red[r][2] + red[r][3];
        float sq = red[r][4] + red[r][5] + red[r][6] + red[r][7];
        float mean = sm * (1.f / EMB);
        float var = sq * (1.f / EMB) - mean * mean;
        float rstd = rsqrtf(var + 1e-5f);
        const float4* g4 = (const float4*)(v1 + p * 32);
        const float4* be4 = (const float4*)(v2 + p * 32);
#pragma unroll
        for (int i = 0; i < 8; i++) {
            float4 gv = g4[i], bv = be4[i];
            vals[4 * i]     = (vals[4 * i]     - mean) * rstd * gv.x + bv.x;
            vals[4 * i + 1] = (vals[4 * i + 1] - mean) * rstd * gv.y + bv.y;
            vals[4 * i + 2] = (vals[4 * i + 2] - mean) * rstd * gv.z + bv.z;
            vals[4 * i + 3] = (vals[4 * i + 3] - mean) * rstd * gv.w + bv.w;
        }
        if (MODE == 1) {
            if (n < N_NODES) {
                float* op = out_nodes + (size_t)n * EMB + p * 32;
#pragma unroll
                for (int i = 0; i < 8; i++)
                    *(float4*)(op + 4 * i) = make_float4(vals[4 * i], vals[4 * i + 1],
                                                         vals[4 * i + 2], vals[4 * i + 3]);
            }
        } else {
            int nvalid = min(64, N_NODES - n0);
            int bmin = bids[0], bmax = bids[nvalid - 1];
            int bid = bids[r];
            bool inA = (bid == bmin) && (n < N_NODES);
            bool inB = (bid == bmax) && (bmax != bmin) && (n < N_NODES);
            if (n < N_NODES && bid != bmin && bid != bmax) {
#pragma unroll
                for (int i = 0; i < 32; i++)
                    atomicAdd(&gsum[(size_t)bid * EMB + p * 32 + i], vals[i]);
            }
#pragma unroll
            for (int g = 0; g < 2; g++) {
                bool m = g ? inB : inA;
#pragma unroll
                for (int i = 0; i < 32; i++) {
                    float v = m ? vals[i] : 0.f;
                    v += __shfl_xor(v, 4, 64);
                    v += __shfl_xor(v, 8, 64);
                    v += __shfl_xor(v, 16, 64);
                    v += __shfl_xor(v, 32, 64);
                    if ((lane >> 2) == 0) locw[wave][g][(lane & 3) * 32 + i] = v;
                }
            }
            __syncthreads();
            if (t < 128) {
                float sA = locw[0][0][t] + locw[1][0][t] + locw[2][0][t] + locw[3][0][t];
                atomicAdd(&gsum[(size_t)bmin * EMB + t], sA);
                if (bmax != bmin) {
                    float sB = locw[0][1][t] + locw[1][1][t] + locw[2][1][t] + locw[3][1][t];
                    atomicAdd(&gsum[(size_t)bmax * EMB + t], sB);
                }
            } else if (t == 255) {
                int cA = 0, cB = 0;
                for (int rr = 0; rr < nvalid; rr++) {
                    int bb = bids[rr];
                    if (bb == bmin) cA++;
                    else if (bb == bmax) cB++;
                    else atomicAdd(&gcnt[bb], 1.f);
                }
                atomicAdd(&gcnt[bmin], (float)cA);
                if (bmax != bmin && cB > 0) atomicAdd(&gcnt[bmax], (float)cB);
            }
        }
    }
}

// ---------------------------------------------------------------------------
// gather: wave per node; CSR walk; softmax-weighted sum of bf16 xs[src];
// fused /denom + bias + LN + ELU; writes packed bf16 h. Zero atomics.
// ---------------------------------------------------------------------------
__global__ __launch_bounds__(256) void gat_gather_kernel(const int* __restrict__ off,
                                                         const int* __restrict__ csr_src,
                                                         const float* __restrict__ csr_ae,
                                                         const unsigned int* __restrict__ xs,
                                                         const float* __restrict__ a_s,
                                                         const float* __restrict__ a_d,
                                                         const float* __restrict__ bias_l,
                                                         const float* __restrict__ gamma_l,
                                                         const float* __restrict__ beta_l,
                                                         unsigned int* __restrict__ h_bf) {
    int t = threadIdx.x, wave = t >> 6, lane = t & 63;
    int n = blockIdx.x * 4 + wave;  // grid = N/4 exactly
    int c0 = lane * 2, c1 = c0 + 1;
    int h = lane >> 4;
    float ad = a_d[(size_t)n * 4 + h];
    int p0 = __builtin_amdgcn_readfirstlane(off[n]);
    int p1 = __builtin_amdgcn_readfirstlane(off[n + 1]);
    float den = 0.f, acc0 = 0.f, acc1 = 0.f;
    int p = p0;
    for (; p + 1 < p1; p += 2) {
        int sA = csr_src[p], sB = csr_src[p + 1];
        float aeA = csr_ae[(size_t)p * 4 + h];
        float aeB = csr_ae[(size_t)(p + 1) * 4 + h];
        float asA = a_s[(size_t)sA * 4 + h];
        float asB = a_s[(size_t)sB * 4 + h];
        unsigned int vA = xs[(size_t)sA * 64 + lane];
        unsigned int vB = xs[(size_t)sB * 64 + lane];
        float alA = asA + ad + aeA;
        alA = alA > 0.f ? alA : 0.2f * alA;
        float exA = __expf(alA);
        float alB = asB + ad + aeB;
        alB = alB > 0.f ? alB : 0.2f * alB;
        float exB = __expf(alB);
        den += exA + exB;
        acc0 += exA * bf2f(vA & 0xFFFFu) + exB * bf2f(vB & 0xFFFFu);
        acc1 += exA * bf2f(vA >> 16) + exB * bf2f(vB >> 16);
    }
    if (p < p1) {
        int s = csr_src[p];
        float ae = csr_ae[(size_t)p * 4 + h];
        float as = a_s[(size_t)s * 4 + h];
        unsigned int v = xs[(size_t)s * 64 + lane];
        float al = as + ad + ae;
        al = al > 0.f ? al : 0.2f * al;
        float ex = __expf(al);
        den += ex;
        acc0 += ex * bf2f(v & 0xFFFFu);
        acc1 += ex * bf2f(v >> 16);
    }
    float dinv = 1.0f / (den + 1e-16f);
    float v0 = acc0 * dinv + bias_l[c0];
    float v1 = acc1 * dinv + bias_l[c1];
    float sm = v0 + v1, sq = v0 * v0 + v1 * v1;
#pragma unroll
    for (int o = 32; o >= 1; o >>= 1) {
        sm += __shfl_down(sm, o, 64);
        sq += __shfl_down(sq, o, 64);
    }
    sm = __shfl(sm, 0, 64);
    sq = __shfl(sq, 0, 64);
    float mean = sm * (1.f / EMB);
    float var = sq * (1.f / EMB) - mean * mean;
    float rstd = rsqrtf(var + 1e-5f);
    float y0 = (v0 - mean) * rstd * gamma_l[c0] + beta_l[c0];
    float y1 = (v1 - mean) * rstd * gamma_l[c1] + beta_l[c1];
    y0 = y0 > 0.f ? y0 : __expf(y0) - 1.f;  // elu
    y1 = y1 > 0.f ? y1 : __expf(y1) - 1.f;
    h_bf[(size_t)n * 64 + lane] = pack2bf(y0, y1);
}

__global__ void graph_out_kernel(const float* __restrict__ gsum, const float* __restrict__ gcnt,
                                 float* __restrict__ out) {
    int i = blockIdx.x * blockDim.x + threadIdx.x;
    if (i >= NGRAPH * EMB) return;
    int b = i >> 7;
    float c = fmaxf(gcnt[b], 1.f);
    out[(size_t)N_NODES * EMB + i] = gsum[i] / c;
}

// ---------------------------------------------------------------------------
extern "C" void kernel_launch(void* const* d_in, const int* in_sizes, int n_in,
                              void* d_out, int out_size, void* d_ws, size_t ws_size,
                              hipStream_t stream) {
    (void)in_sizes; (void)n_in; (void)out_size; (void)ws_size;
    const float* x         = (const float*)d_in[0];
    const float* edge_attr = (const float*)d_in[1];
    const float* W_in      = (const float*)d_in[2];
    const float* b_in      = (const float*)d_in[3];
    const float* W_src     = (const float*)d_in[4];
    const float* W_edge    = (const float*)d_in[5];
    const float* att_src   = (const float*)d_in[6];
    const float* att_dst   = (const float*)d_in[7];
    const float* att_edge  = (const float*)d_in[8];
    const float* gat_bias  = (const float*)d_in[9];
    const float* ln_gamma  = (const float*)d_in[10];
    const float* ln_beta   = (const float*)d_in[11];
    const float* W_out     = (const float*)d_in[12];
    const float* b_out     = (const float*)d_in[13];
    const float* ln_og     = (const float*)d_in[14];
    const float* ln_ob     = (const float*)d_in[15];
    const float* W_g       = (const float*)d_in[16];
    const float* b_g       = (const float*)d_in[17];
    const float* g_gamma   = (const float*)d_in[18];
    const float* g_beta    = (const float*)d_in[19];
    const int* edge_index  = (const int*)d_in[20];
    const int* batch       = (const int*)d_in[21];
    float* out = (float*)d_out;

    float* ws              = (float*)d_ws;
    unsigned int* h_bf     = (unsigned int*)ws;               // N*64
    unsigned int* xs       = h_bf + (size_t)N_NODES * 64;     // N*64
    unsigned int* x_bf     = xs + (size_t)N_NODES * 64;       // N*16
    float* a_s             = (float*)(x_bf + (size_t)N_NODES * 16);  // N*4
    float* a_d             = a_s + (size_t)N_NODES * 4;       // N*4
    float* csr_ae          = a_d + (size_t)N_NODES * 4;       // 2*E2*4
    unsigned short* gwt    = (unsigned short*)(csr_ae + (size_t)2 * E2 * 4);  // 73728 shorts
    float* meta            = (float*)(gwt + GWT_TOT);         // 152
    float* gsum            = meta + 152;                      // 1024
    float* gcnt            = gsum + NGRAPH * EMB;             // 8
    int*   cnt4            = (int*)(gcnt + NGRAPH);           // 4*N
    int*   off             = cnt4 + 4 * N_NODES;              // N+1
    int*   shard_base      = off + N_NODES + 1;               // 4*N
    int*   rank            = shard_base + 4 * N_NODES;        // E2
    int*   csr_src         = rank + E2;                       // E2
    int*   bsum            = csr_src + E2;                    // NBLK
    int*   bbase           = bsum + NBLK;                     // NBLK
    // total ~16.6M words = 66.3 MB (< 75.8 proven in round 8)

    const int EB = (E2 + 255) / 256;  // 3321

    zero_kernel<<<256, 256, 0, stream>>>(meta, 152 + NGRAPH * EMB + NGRAPH + 4 * N_NODES);
    mean_kernel<<<2048, 256, 0, stream>>>(edge_attr, meta);
    prep_kernel<<<1, 128, 0, stream>>>(W_edge, att_edge, meta);
    prep_wt_kernel<<<36, 256, 0, stream>>>(W_src, W_out, W_g, gwt);
    input_proj_kernel<<<NB32, 256, 0, stream>>>(x, W_in, b_in, h_bf, x_bf);

    count_rank_kernel<<<EB, 256, 0, stream>>>(edge_index, cnt4, rank);
    scan1_kernel<<<NBLK, 256, 0, stream>>>(cnt4, bsum);
    scan2_kernel<<<1, 256, 0, stream>>>(bsum, bbase);
    scan3_kernel<<<NBLK, 256, 0, stream>>>(bbase, cnt4, off, shard_base);
    fill_ae_kernel<<<EB, 256, 0, stream>>>(edge_index, edge_attr, meta, rank, shard_base,
                                           csr_src, csr_ae, csr_ae + (size_t)E2 * 4);

    for (int l = 0; l < NLAYER; l++) {
        dense_mfma_kernel<GAT_IN, 0><<<NB64, 256, 0, stream>>>(
            x_bf, h_bf, gwt + (l ? GWT_SRC1 : GWT_SRC0), nullptr,
            att_src + (size_t)l * EMB, att_dst + (size_t)l * EMB, nullptr,
            xs, a_s, a_d, nullptr, nullptr, nullptr);
        gat_gather_kernel<<<N_NODES / 4, 256, 0, stream>>>(
            off, csr_src, csr_ae + (size_t)l * E2 * 4, xs, a_s, a_d,
            gat_bias + (size_t)l * EMB, ln_gamma + (size_t)l * EMB,
            ln_beta + (size_t)l * EMB, h_bf);
    }

    dense_mfma_kernel<EMB, 1><<<NB64, 256, 0, stream>>>(
        nullptr, h_bf, gwt + GWT_OUT, b_out, ln_og, ln_ob, nullptr,
        nullptr, nullptr, nullptr, out, nullptr, nullptr);
    dense_mfma_kernel<EMB, 2><<<NB64, 256, 0, stream>>>(
        nullptr, h_bf, gwt + GWT_G, b_g, g_gamma, g_beta, batch,
        nullptr, nullptr, nullptr, nullptr, gsum, gcnt);
    graph_out_kernel<<<4, 256, 0, stream>>>(gsum, gcnt, out);
}